// Round 13
// baseline (502.380 us; speedup 1.0000x reference)
//
#include <hip/hip_runtime.h>

#define NH 64
#define NCLS 2
#define HWC 32768  // histogram window (nodes per range), 128KB LDS
#define HCHC 32    // edge chunks per range

typedef short short8 __attribute__((ext_vector_type(8)));
typedef float f32x4 __attribute__((ext_vector_type(4)));

__device__ inline unsigned short f2bf(float x) {
    unsigned u = __float_as_uint(x);
    unsigned r = (u + 0x7FFFu + ((u >> 16) & 1u)) >> 16;
    return (unsigned short)r;
}
__device__ inline float bf2f(unsigned short h) { return __uint_as_float(((unsigned)h) << 16); }
__device__ inline float bf2f_u(unsigned h) { return __uint_as_float(h << 16); }

__device__ inline void acc_u4(uint4 u, float4& am, float4& av) {
    am.x += __uint_as_float(u.x << 16);
    av.x += __uint_as_float(u.x & 0xffff0000u);
    am.y += __uint_as_float(u.y << 16);
    av.y += __uint_as_float(u.y & 0xffff0000u);
    am.z += __uint_as_float(u.z << 16);
    av.z += __uint_as_float(u.z & 0xffff0000u);
    am.w += __uint_as_float(u.w << 16);
    av.w += __uint_as_float(u.w & 0xffff0000u);
}

// ---------------- degree count: atomic-free two-level histogram ----------------

__launch_bounds__(256)
__global__ void count_hist(const int* __restrict__ dst, int* __restrict__ partial,
                           int E, int n) {
    __shared__ int hist[HWC];
    const int tid = threadIdx.x;
    const int range = blockIdx.x / HCHC, chunk = blockIdx.x - range * HCHC;
    const int lo = range * HWC;
    const int hi = min(lo + HWC, n);
    for (int i = tid * 4; i < HWC; i += 1024) *(int4*)&hist[i] = make_int4(0, 0, 0, 0);
    __syncthreads();
    int cbeg = ((int)((long long)chunk * E / HCHC)) & ~3;
    int cend = (chunk == HCHC - 1) ? E : (((int)((long long)(chunk + 1) * E / HCHC)) & ~3);
    int aend = cbeg + ((cend - cbeg) & ~3);
    for (int i = cbeg + tid * 4; i + 3 < cend; i += 1024) {
        int4 d = *(const int4*)(dst + i);
        if (d.x >= lo && d.x < hi) atomicAdd(&hist[d.x - lo], 1);
        if (d.y >= lo && d.y < hi) atomicAdd(&hist[d.y - lo], 1);
        if (d.z >= lo && d.z < hi) atomicAdd(&hist[d.z - lo], 1);
        if (d.w >= lo && d.w < hi) atomicAdd(&hist[d.w - lo], 1);
    }
    if (tid < cend - aend) {
        int d = dst[aend + tid];
        if (d >= lo && d < hi) atomicAdd(&hist[d - lo], 1);
    }
    __syncthreads();
    int* pout = partial + ((size_t)range * HCHC + chunk) * HWC;
    for (int i = tid * 4; i < HWC; i += 1024) *(int4*)&pout[i] = *(const int4*)&hist[i];
}

// block exclusive scan over deg (deg computed on the fly from the partials)
__global__ void scan1p(const int* __restrict__ partial, int* __restrict__ out,
                       int* __restrict__ bsum, int n) {
    __shared__ int s[256];
    int tid = threadIdx.x;
    int base = blockIdx.x * 1024 + tid * 4;
    int4 acc = make_int4(0, 0, 0, 0);
    if (base < n) {
        int r = base / HWC;
        int ii = base - r * HWC;
        const int* pr = partial + (size_t)r * HCHC * HWC + ii;
#pragma unroll 8
        for (int k = 0; k < HCHC; ++k) {
            int4 v = *(const int4*)(pr + (size_t)k * HWC);
            acc.x += v.x;
            acc.y += v.y;
            acc.z += v.z;
            acc.w += v.w;
        }
    }
    int v0 = (base + 0 < n) ? acc.x : 0;
    int v1 = (base + 1 < n) ? acc.y : 0;
    int v2 = (base + 2 < n) ? acc.z : 0;
    int v3 = (base + 3 < n) ? acc.w : 0;
    int lsum = v0 + v1 + v2 + v3;
    s[tid] = lsum;
    __syncthreads();
    for (int off = 1; off < 256; off <<= 1) {
        int t = (tid >= off) ? s[tid - off] : 0;
        __syncthreads();
        s[tid] += t;
        __syncthreads();
    }
    int excl = s[tid] - lsum;
    if (base + 0 < n) out[base + 0] = excl;
    if (base + 1 < n) out[base + 1] = excl + v0;
    if (base + 2 < n) out[base + 2] = excl + v0 + v1;
    if (base + 3 < n) out[base + 3] = excl + v0 + v1 + v2;
    if (tid == 255) bsum[blockIdx.x] = s[255];
}

__global__ void scan2(const int* __restrict__ bsum, int* __restrict__ boff, int nb) {
    __shared__ int s[256];
    int tid = threadIdx.x;
    int v = (tid < nb) ? bsum[tid] : 0;
    s[tid] = v;
    __syncthreads();
    for (int off = 1; off < 256; off <<= 1) {
        int t = (tid >= off) ? s[tid - off] : 0;
        __syncthreads();
        s[tid] += t;
        __syncthreads();
    }
    if (tid < nb) boff[tid] = s[tid] - v;
}

__global__ void scan3(int* __restrict__ rowptr, const int* __restrict__ boff,
                      int n, int total) {
    int i = blockIdx.x * 256 + threadIdx.x;
    if (i < n) rowptr[i] += boff[i >> 10];
    else if (i == n) rowptr[n] = total;
}

// convert partial counts -> absolute col starting offsets (per node, per chunk)
__global__ void cumpart(int* __restrict__ partial, const int* __restrict__ rowptr, int n) {
    int i = blockIdx.x * 256 + threadIdx.x;
    if (i >= n) return;
    int r = i / HWC, ii = i - r * HWC;
    int* base = partial + (size_t)r * HCHC * HWC + ii;
    int run = rowptr[i];
#pragma unroll 8
    for (int k = 0; k < HCHC; ++k) {
        int v = base[(size_t)k * HWC];
        base[(size_t)k * HWC] = run;
        run += v;
    }
}

// atomic-free CSR fill: block (range,chunk), LDS cursors seeded from cumpart offsets
__launch_bounds__(256)
__global__ void fill_hist(const int* __restrict__ src, const int* __restrict__ dst,
                          const int* __restrict__ partial, int* __restrict__ col,
                          int E, int n) {
    __shared__ int cur[HWC];
    const int tid = threadIdx.x;
    const int range = blockIdx.x / HCHC, chunk = blockIdx.x - range * HCHC;
    const int lo = range * HWC;
    const int hi = min(lo + HWC, n);
    const int* pin = partial + ((size_t)range * HCHC + chunk) * HWC;
    for (int i = tid * 4; i < HWC; i += 1024) *(int4*)&cur[i] = *(const int4*)&pin[i];
    __syncthreads();
    int cbeg = ((int)((long long)chunk * E / HCHC)) & ~3;
    int cend = (chunk == HCHC - 1) ? E : (((int)((long long)(chunk + 1) * E / HCHC)) & ~3);
    int aend = cbeg + ((cend - cbeg) & ~3);
    for (int i = cbeg + tid * 4; i + 3 < cend; i += 1024) {
        int4 d = *(const int4*)(dst + i);
        int4 sv = *(const int4*)(src + i);
        if (d.x >= lo && d.x < hi) col[atomicAdd(&cur[d.x - lo], 1)] = sv.x;
        if (d.y >= lo && d.y < hi) col[atomicAdd(&cur[d.y - lo], 1)] = sv.y;
        if (d.z >= lo && d.z < hi) col[atomicAdd(&cur[d.z - lo], 1)] = sv.z;
        if (d.w >= lo && d.w < hi) col[atomicAdd(&cur[d.w - lo], 1)] = sv.w;
    }
    if (tid < cend - aend) {
        int d = dst[aend + tid];
        if (d >= lo && d < hi) col[atomicAdd(&cur[d - lo], 1)] = src[aend + tid];
    }
}

// ---------------- weight prep (all 6 sets in one kernel) ----------------

__device__ void prep_one(const float* __restrict__ Wl, const float* __restrict__ Wr,
                         const float* __restrict__ bl, int K,
                         unsigned short* __restrict__ Wth, unsigned short* __restrict__ Wtl,
                         float* __restrict__ biasOut, int gid, int gsz) {
    int tot = 128 * K;
    for (int idx = gid; idx < tot; idx += gsz) {
        int c = idx / K, k = idx - c * K;
        float wv = (c < 64) ? Wl[(size_t)k * 64 + c] : Wr[(size_t)k * 64 + (c - 64)];
        unsigned short h = f2bf(wv);
        Wth[idx] = h;
        Wtl[idx] = f2bf(wv - bf2f(h));
    }
    for (int idx = gid; idx < 128; idx += gsz)
        biasOut[idx] = (idx < 64) ? 0.f : bl[idx - 64];
}

__global__ void prep_all(const float* __restrict__ m0Wl, const float* __restrict__ m0Wr,
                         const float* __restrict__ m0bl,
                         const float* __restrict__ v0Wl, const float* __restrict__ v0Wr,
                         const float* __restrict__ v0bl,
                         const float* __restrict__ mRWl, const float* __restrict__ mRWr,
                         const float* __restrict__ mRbl,
                         const float* __restrict__ vRWl, const float* __restrict__ vRWr,
                         const float* __restrict__ vRbl,
                         unsigned short* __restrict__ w0h, unsigned short* __restrict__ w0l,
                         unsigned short* __restrict__ wlh, unsigned short* __restrict__ wll,
                         float* __restrict__ biasAll) {
    int gid = blockIdx.x * 256 + threadIdx.x;
    int gsz = gridDim.x * 256;
    prep_one(m0Wl, m0Wr, m0bl, 128, w0h, w0l, biasAll, gid, gsz);
    prep_one(v0Wl, v0Wr, v0bl, 128, w0h + 128 * 128, w0l + 128 * 128, biasAll + 128, gid, gsz);
    for (int i = 0; i < 2; ++i) {
        prep_one(mRWl + (size_t)i * 4096, mRWr + (size_t)i * 4096, mRbl + (size_t)i * 64, 64,
                 wlh + (size_t)(2 * i) * 8192, wll + (size_t)(2 * i) * 8192,
                 biasAll + (2 + 2 * i) * 128, gid, gsz);
        prep_one(vRWl + (size_t)i * 4096, vRWr + (size_t)i * 4096, vRbl + (size_t)i * 64, 64,
                 wlh + (size_t)(2 * i + 1) * 8192, wll + (size_t)(2 * i + 1) * 8192,
                 biasAll + (2 + 2 * i + 1) * 128, gid, gsz);
    }
}

// ---------------- dual-path split-bf16 MFMA GEMM, fp32 A from global ----------------
// A fragments for both paths hoisted to the top of each K-phase (latency hidden
// under B staging + barriers). Output TLRu[r*128+c] = bf16(mean)|bf16(var)<<16.

__launch_bounds__(256)
__global__ void gemm_dual(const float* __restrict__ Am, const float* __restrict__ Av,
                          const unsigned short* __restrict__ Wh,  // [2][128*Kg]
                          const unsigned short* __restrict__ Wl,  // [2][128*Kg]
                          const float* __restrict__ bias,         // [2][128]
                          unsigned* __restrict__ TLRu, int Kg, int Nn) {
    __shared__ unsigned short Bh[128 * 72], Bl[128 * 72];
    const int tid = threadIdx.x;
    const int l = tid & 63, w = tid >> 6;
    const int rowbase = blockIdx.x * 64;
    const int r = rowbase + w * 16 + (l & 15);
    const bool rok = r < Nn;
    const int kofs = (l >> 4) * 8;
    f32x4 acc[2][8] = {};

    bool first = true;
    for (int k0 = 0; k0 < Kg; k0 += 64) {
        // hoisted A fragments: [path][kk]
        short8 ah0_0 = {}, al0_0 = {}, ah0_1 = {}, al0_1 = {};
        short8 ah1_0 = {}, al1_0 = {}, ah1_1 = {}, al1_1 = {};
        if (rok) {
#pragma unroll
            for (int p2 = 0; p2 < 2; ++p2) {
                const float* As = p2 ? Av : Am;
#pragma unroll
                for (int kk2 = 0; kk2 < 2; ++kk2) {
                    const float* xr = As + (size_t)r * Kg + k0 + kofs + kk2 * 32;
                    float4 v0 = *(const float4*)xr;
                    float4 v1 = *(const float4*)(xr + 4);
                    float f[8] = {v0.x, v0.y, v0.z, v0.w, v1.x, v1.y, v1.z, v1.w};
                    short8 hh, ll;
#pragma unroll
                    for (int i = 0; i < 8; ++i) {
                        unsigned short h = f2bf(f[i]);
                        hh[i] = (short)h;
                        ll[i] = (short)f2bf(f[i] - bf2f(h));
                    }
                    if (p2 == 0 && kk2 == 0) { ah0_0 = hh; al0_0 = ll; }
                    else if (p2 == 0) { ah0_1 = hh; al0_1 = ll; }
                    else if (kk2 == 0) { ah1_0 = hh; al1_0 = ll; }
                    else { ah1_1 = hh; al1_1 = ll; }
                }
            }
        }
#pragma unroll
        for (int p = 0; p < 2; ++p) {
            if (!first) __syncthreads();
            first = false;
            // stage B (one path) into LDS
#pragma unroll
            for (int q = 0; q < 4; ++q) {
                int lin = q * 256 + tid;
                int c = lin >> 3;
                int k8 = (lin & 7) << 3;
                *(short8*)&Bh[c * 72 + k8] =
                    *(const short8*)(Wh + (size_t)p * 128 * Kg + (size_t)c * Kg + k0 + k8);
                *(short8*)&Bl[c * 72 + k8] =
                    *(const short8*)(Wl + (size_t)p * 128 * Kg + (size_t)c * Kg + k0 + k8);
            }
            __syncthreads();
#pragma unroll
            for (int kk = 0; kk < 2; ++kk) {
                short8 a_h = (p == 0) ? (kk == 0 ? ah0_0 : ah0_1) : (kk == 0 ? ah1_0 : ah1_1);
                short8 a_l = (p == 0) ? (kk == 0 ? al0_0 : al0_1) : (kk == 0 ? al1_0 : al1_1);
#pragma unroll
                for (int ct = 0; ct < 8; ++ct) {
                    const int br = (ct * 16 + (l & 15)) * 72 + kk * 32 + kofs;
                    short8 b_h = *(const short8*)&Bh[br];
                    short8 b_l = *(const short8*)&Bl[br];
                    acc[p][ct] = __builtin_amdgcn_mfma_f32_16x16x32_bf16(a_h, b_h, acc[p][ct], 0, 0, 0);
                    acc[p][ct] = __builtin_amdgcn_mfma_f32_16x16x32_bf16(a_h, b_l, acc[p][ct], 0, 0, 0);
                    acc[p][ct] = __builtin_amdgcn_mfma_f32_16x16x32_bf16(a_l, b_h, acc[p][ct], 0, 0, 0);
                }
            }
        }
    }
    const int r0 = rowbase + w * 16 + ((l >> 4) << 2);
#pragma unroll
    for (int ct = 0; ct < 8; ++ct) {
        int c = ct * 16 + (l & 15);
        float b0 = bias[c];
        float b1 = bias[128 + c];
#pragma unroll
        for (int i = 0; i < 4; ++i) {
            int rr = r0 + i;
            if (rr < Nn) {
                unsigned hm = f2bf(acc[0][ct][i] + b0);
                unsigned hv = f2bf(acc[1][ct][i] + b1);
                TLRu[(size_t)rr * 128 + c] = hm | (hv << 16);
            }
        }
    }
}

// ---------------- fused CSR aggregate (mean+var): relu(agg(TL)/deg + TR) ----------------

__launch_bounds__(256)
__global__ void agg_fused(const unsigned* __restrict__ TLRu,
                          const int* __restrict__ rowptr, const int* __restrict__ col,
                          float* __restrict__ outm, float* __restrict__ outv, int n) {
    int node = blockIdx.x * 16 + (threadIdx.x >> 4);
    if (node >= n) return;
    const int sub = threadIdx.x & 15;
    const int s = rowptr[node], e = rowptr[node + 1];
    float4 am0 = {0, 0, 0, 0}, av0 = {0, 0, 0, 0};
    float4 am1 = {0, 0, 0, 0}, av1 = {0, 0, 0, 0};
    int j = s;
    for (; j + 8 <= e; j += 8) {
        int c0 = col[j], c1 = col[j + 1], c2 = col[j + 2], c3 = col[j + 3];
        int c4 = col[j + 4], c5 = col[j + 5], c6 = col[j + 6], c7 = col[j + 7];
        uint4 u0 = ((const uint4*)(TLRu + (size_t)c0 * 128))[sub];
        uint4 u1 = ((const uint4*)(TLRu + (size_t)c1 * 128))[sub];
        uint4 u2 = ((const uint4*)(TLRu + (size_t)c2 * 128))[sub];
        uint4 u3 = ((const uint4*)(TLRu + (size_t)c3 * 128))[sub];
        uint4 u4 = ((const uint4*)(TLRu + (size_t)c4 * 128))[sub];
        uint4 u5 = ((const uint4*)(TLRu + (size_t)c5 * 128))[sub];
        uint4 u6 = ((const uint4*)(TLRu + (size_t)c6 * 128))[sub];
        uint4 u7 = ((const uint4*)(TLRu + (size_t)c7 * 128))[sub];
        acc_u4(u0, am0, av0);
        acc_u4(u1, am1, av1);
        acc_u4(u2, am0, av0);
        acc_u4(u3, am1, av1);
        acc_u4(u4, am0, av0);
        acc_u4(u5, am1, av1);
        acc_u4(u6, am0, av0);
        acc_u4(u7, am1, av1);
    }
    if (j + 4 <= e) {
        int c0 = col[j], c1 = col[j + 1], c2 = col[j + 2], c3 = col[j + 3];
        uint4 u0 = ((const uint4*)(TLRu + (size_t)c0 * 128))[sub];
        uint4 u1 = ((const uint4*)(TLRu + (size_t)c1 * 128))[sub];
        uint4 u2 = ((const uint4*)(TLRu + (size_t)c2 * 128))[sub];
        uint4 u3 = ((const uint4*)(TLRu + (size_t)c3 * 128))[sub];
        acc_u4(u0, am0, av0);
        acc_u4(u1, am1, av1);
        acc_u4(u2, am0, av0);
        acc_u4(u3, am1, av1);
        j += 4;
    }
    for (; j < e; ++j) {
        int c0 = col[j];
        uint4 u0 = ((const uint4*)(TLRu + (size_t)c0 * 128))[sub];
        acc_u4(u0, am0, av0);
    }
    am0.x += am1.x; am0.y += am1.y; am0.z += am1.z; am0.w += am1.w;
    av0.x += av1.x; av0.y += av1.y; av0.z += av1.z; av0.w += av1.w;

    float inv = 1.0f / (float)max(e - s, 1);
    uint4 t = ((const uint4*)(TLRu + (size_t)node * 128 + 64))[sub];
    float vm0 = fmaxf(fmaf(am0.x, inv, bf2f_u(t.x & 0xffff)), 0.f);
    float vv0 = fmaxf(fmaf(av0.x, inv, __uint_as_float(t.x & 0xffff0000u)), 0.f);
    float vm1 = fmaxf(fmaf(am0.y, inv, bf2f_u(t.y & 0xffff)), 0.f);
    float vv1 = fmaxf(fmaf(av0.y, inv, __uint_as_float(t.y & 0xffff0000u)), 0.f);
    float vm2 = fmaxf(fmaf(am0.z, inv, bf2f_u(t.z & 0xffff)), 0.f);
    float vv2 = fmaxf(fmaf(av0.z, inv, __uint_as_float(t.z & 0xffff0000u)), 0.f);
    float vm3 = fmaxf(fmaf(am0.w, inv, bf2f_u(t.w & 0xffff)), 0.f);
    float vv3 = fmaxf(fmaf(av0.w, inv, __uint_as_float(t.w & 0xffff0000u)), 0.f);
    size_t o = (size_t)node * 64 + sub * 4;
    *(float4*)(outm + o) = make_float4(vm0, vm1, vm2, vm3);
    *(float4*)(outv + o) = make_float4(vv0, vv1, vv2, vv3);
}

// ---------------- per-group: reparam + mean-pool + fc1 + relu + fc2 + log_softmax ----------------

__launch_bounds__(256)
__global__ void pool_head(const float* __restrict__ mean, const float* __restrict__ logv,
                          const float* __restrict__ eps, const int* __restrict__ batch,
                          const float* __restrict__ fc1W, const float* __restrict__ fc1b,
                          const float* __restrict__ fc2W, const float* __restrict__ fc2b,
                          float* __restrict__ out, int n) {
    __shared__ int se[2];
    __shared__ float4 red[256];
    __shared__ float pooled[64];
    __shared__ float hbuf[128];
    __shared__ float lg[2];
    const int g = blockIdx.x, tid = threadIdx.x;
    if (tid == 0 || tid == 64) {
        int key = g + (tid >> 6);
        int a = 0, b = n;
        while (a < b) {
            int m = (a + b) >> 1;
            if (batch[m] < key) a = m + 1;
            else b = m;
        }
        se[tid >> 6] = a;
    }
    __syncthreads();
    const int s = se[0], e = se[1];
    const int nof = tid >> 4, fq = tid & 15;
    float4 acc = make_float4(0.f, 0.f, 0.f, 0.f);
    for (int i = s + nof; i < e; i += 16) {
        size_t o = (size_t)i * 64 + fq * 4;
        float4 m4 = *(const float4*)(mean + o);
        float4 l4 = *(const float4*)(logv + o);
        float4 e4 = *(const float4*)(eps + o);
        acc.x += m4.x + e4.x * expf(0.5f * l4.x);
        acc.y += m4.y + e4.y * expf(0.5f * l4.y);
        acc.z += m4.z + e4.z * expf(0.5f * l4.z);
        acc.w += m4.w + e4.w * expf(0.5f * l4.w);
    }
    red[tid] = acc;
    __syncthreads();
    if (tid < 16) {
        float4 sum = red[fq];
        for (int j = 1; j < 16; ++j) {
            float4 r = red[j * 16 + fq];
            sum.x += r.x;
            sum.y += r.y;
            sum.z += r.z;
            sum.w += r.w;
        }
        float inv = 1.0f / (float)max(e - s, 1);
        pooled[fq * 4 + 0] = sum.x * inv;
        pooled[fq * 4 + 1] = sum.y * inv;
        pooled[fq * 4 + 2] = sum.z * inv;
        pooled[fq * 4 + 3] = sum.w * inv;
    }
    __syncthreads();
    if (tid < 128) {
        float a = fc1b[tid];
        for (int k = 0; k < 64; ++k) a = fmaf(pooled[k], fc1W[k * 128 + tid], a);
        hbuf[tid] = fmaxf(a, 0.f);
    }
    __syncthreads();
    if (tid < 2) {
        float a = fc2b[tid];
        for (int k = 0; k < 128; ++k) a = fmaf(hbuf[k], fc2W[k * 2 + tid], a);
        lg[tid] = a;
    }
    __syncthreads();
    if (tid < 2) {
        float m = fmaxf(lg[0], lg[1]);
        float lse = m + logf(expf(lg[0] - m) + expf(lg[1] - m));
        out[(size_t)g * 2 + tid] = lg[tid] - lse;
    }
}

extern "C" void kernel_launch(void* const* d_in, const int* in_sizes, int n_in,
                              void* d_out, int out_size, void* d_ws, size_t ws_size,
                              hipStream_t stream) {
    const int N = in_sizes[19];
    const int E = in_sizes[18] / 2;
    const int G = (out_size - 2 * N * NH) / NCLS;

    const float* x    = (const float*)d_in[0];
    const float* eps  = (const float*)d_in[1];
    const float* m0Wl = (const float*)d_in[2];
    const float* m0bl = (const float*)d_in[3];
    const float* m0Wr = (const float*)d_in[4];
    const float* mRWl = (const float*)d_in[5];
    const float* mRbl = (const float*)d_in[6];
    const float* mRWr = (const float*)d_in[7];
    const float* v0Wl = (const float*)d_in[8];
    const float* v0bl = (const float*)d_in[9];
    const float* v0Wr = (const float*)d_in[10];
    const float* vRWl = (const float*)d_in[11];
    const float* vRbl = (const float*)d_in[12];
    const float* vRWr = (const float*)d_in[13];
    const float* fc1W = (const float*)d_in[14];
    const float* fc1b = (const float*)d_in[15];
    const float* fc2W = (const float*)d_in[16];
    const float* fc2b = (const float*)d_in[17];
    const int* eidx   = (const int*)d_in[18];
    const int* batch  = (const int*)d_in[19];
    const int* srcI = eidx;
    const int* dstI = eidx + E;

    float* out_ls = (float*)d_out;
    float* out_mean = out_ls + (size_t)G * NCLS;
    float* out_lv = out_mean + (size_t)N * NH;

    char* w = (char*)d_ws;
    auto alloc = [&](size_t bytes) {
        char* p = w;
        w += (bytes + 255) & ~(size_t)255;
        return p;
    };
    int* rowptr = (int*)alloc((size_t)(N + 1) * 4);
    int* bsum = (int*)alloc(256 * 4);
    int* boff = (int*)alloc(256 * 4);
    int* col = (int*)alloc((size_t)E * 4);
    unsigned* TLRu = (unsigned*)alloc((size_t)N * 128 * 4);  // packed mean|var (also hist scratch)
    unsigned short* w0h = (unsigned short*)alloc(2 * 128 * 128 * 2);
    unsigned short* w0l = (unsigned short*)alloc(2 * 128 * 128 * 2);
    unsigned short* wlh = (unsigned short*)alloc(4 * 128 * 64 * 2);
    unsigned short* wll = (unsigned short*)alloc(4 * 128 * 64 * 2);
    float* biasAll = (float*)alloc(6 * 128 * 4);
    (void)n_in;

    // fp32 inter-layer state: prefer workspace; fall back to d_out placement.
    float* Sm;
    float* Sv;
    size_t used = (size_t)(w - (char*)d_ws);
    if (used + 2 * ((size_t)N * NH * 4 + 256) <= ws_size) {
        Sm = (float*)alloc((size_t)N * NH * 4);
        Sv = (float*)alloc((size_t)N * NH * 4);
    } else {
        Sm = out_mean;
        Sv = out_lv;
    }

    const int nbScan = (N + 1023) / 1024;
    const int nbR = (N + 63) / 64;
    const int nbAgg = (N + 15) / 16;
    const int nRange = (N + HWC - 1) / HWC;

    // weight prep
    prep_all<<<128, 256, 0, stream>>>(m0Wl, m0Wr, m0bl, v0Wl, v0Wr, v0bl,
                                      mRWl, mRWr, mRbl, vRWl, vRWr, vRbl,
                                      w0h, w0l, wlh, wll, biasAll);

    // CSR build: histogram -> rowptr -> cumulative offsets -> atomic-free fill
    int* partial = (int*)TLRu;  // scratch; fully consumed before gemm0 overwrites
    count_hist<<<nRange * HCHC, 256, 0, stream>>>(dstI, partial, E, N);
    scan1p<<<nbScan, 256, 0, stream>>>(partial, rowptr, bsum, N);
    scan2<<<1, 256, 0, stream>>>(bsum, boff, nbScan);
    scan3<<<(N + 256) / 256 + 1, 256, 0, stream>>>(rowptr, boff, N, E);
    cumpart<<<(N + 255) / 256, 256, 0, stream>>>(partial, rowptr, N);
    fill_hist<<<nRange * HCHC, 256, 0, stream>>>(srcI, dstI, partial, col, E, N);

    // layer-0 GEMM (overwrites TLRu after fill consumed the partials)
    gemm_dual<<<nbR, 256, 0, stream>>>(x, x, w0h, w0l, biasAll, TLRu, 128, N);
    agg_fused<<<nbAgg, 256, 0, stream>>>(TLRu, rowptr, col, Sm, Sv, N);

    // layers 1..2 (K=64, fp32 state)
    for (int i = 0; i < 2; ++i) {
        const bool fin = (i == 1);
        gemm_dual<<<nbR, 256, 0, stream>>>(Sm, Sv,
                                           wlh + (size_t)(2 * i) * 8192,
                                           wll + (size_t)(2 * i) * 8192,
                                           biasAll + (2 + 2 * i) * 128, TLRu, 64, N);
        if (fin)
            agg_fused<<<nbAgg, 256, 0, stream>>>(TLRu, rowptr, col, out_mean, out_lv, N);
        else
            agg_fused<<<nbAgg, 256, 0, stream>>>(TLRu, rowptr, col, Sm, Sv, N);
    }

    // reparam + pool + FC head, one block per graph
    pool_head<<<G, 256, 0, stream>>>(out_mean, out_lv, eps, batch, fc1W, fc1b, fc2W, fc2b,
                                     out_ls, N);
}

// Round 14
// 454.880 us; speedup vs baseline: 1.1044x; 1.1044x over previous
//
#include <hip/hip_runtime.h>

#define NH 64
#define NCLS 2
#define HWC 32768  // histogram window (nodes per range), 128KB LDS
#define HCHC 32    // edge chunks per range

typedef short short8 __attribute__((ext_vector_type(8)));
typedef float f32x4 __attribute__((ext_vector_type(4)));

__device__ inline unsigned short f2bf(float x) {
    unsigned u = __float_as_uint(x);
    unsigned r = (u + 0x7FFFu + ((u >> 16) & 1u)) >> 16;
    return (unsigned short)r;
}
__device__ inline float bf2f(unsigned short h) { return __uint_as_float(((unsigned)h) << 16); }
__device__ inline float bf2f_u(unsigned h) { return __uint_as_float(h << 16); }

__device__ inline void acc_u4(uint4 u, float4& am, float4& av) {
    am.x += __uint_as_float(u.x << 16);
    av.x += __uint_as_float(u.x & 0xffff0000u);
    am.y += __uint_as_float(u.y << 16);
    av.y += __uint_as_float(u.y & 0xffff0000u);
    am.z += __uint_as_float(u.z << 16);
    av.z += __uint_as_float(u.z & 0xffff0000u);
    am.w += __uint_as_float(u.w << 16);
    av.w += __uint_as_float(u.w & 0xffff0000u);
}

// ---------------- degree count: atomic-free two-level histogram ----------------

__launch_bounds__(256)
__global__ void count_hist(const int* __restrict__ dst, int* __restrict__ partial,
                           int E, int n) {
    __shared__ int hist[HWC];
    const int tid = threadIdx.x;
    const int range = blockIdx.x / HCHC, chunk = blockIdx.x - range * HCHC;
    const int lo = range * HWC;
    const int hi = min(lo + HWC, n);
    for (int i = tid * 4; i < HWC; i += 1024) *(int4*)&hist[i] = make_int4(0, 0, 0, 0);
    __syncthreads();
    int cbeg = ((int)((long long)chunk * E / HCHC)) & ~3;
    int cend = (chunk == HCHC - 1) ? E : (((int)((long long)(chunk + 1) * E / HCHC)) & ~3);
    int aend = cbeg + ((cend - cbeg) & ~3);
    for (int i = cbeg + tid * 4; i + 3 < cend; i += 1024) {
        int4 d = *(const int4*)(dst + i);
        if (d.x >= lo && d.x < hi) atomicAdd(&hist[d.x - lo], 1);
        if (d.y >= lo && d.y < hi) atomicAdd(&hist[d.y - lo], 1);
        if (d.z >= lo && d.z < hi) atomicAdd(&hist[d.z - lo], 1);
        if (d.w >= lo && d.w < hi) atomicAdd(&hist[d.w - lo], 1);
    }
    if (tid < cend - aend) {
        int d = dst[aend + tid];
        if (d >= lo && d < hi) atomicAdd(&hist[d - lo], 1);
    }
    __syncthreads();
    int* pout = partial + ((size_t)range * HCHC + chunk) * HWC;
    for (int i = tid * 4; i < HWC; i += 1024) *(int4*)&pout[i] = *(const int4*)&hist[i];
}

// block exclusive scan over deg (deg computed on the fly from the partials)
__global__ void scan1p(const int* __restrict__ partial, int* __restrict__ out,
                       int* __restrict__ bsum, int n) {
    __shared__ int s[256];
    int tid = threadIdx.x;
    int base = blockIdx.x * 1024 + tid * 4;
    int4 acc = make_int4(0, 0, 0, 0);
    if (base < n) {
        int r = base / HWC;
        int ii = base - r * HWC;
        const int* pr = partial + (size_t)r * HCHC * HWC + ii;
#pragma unroll 8
        for (int k = 0; k < HCHC; ++k) {
            int4 v = *(const int4*)(pr + (size_t)k * HWC);
            acc.x += v.x;
            acc.y += v.y;
            acc.z += v.z;
            acc.w += v.w;
        }
    }
    int v0 = (base + 0 < n) ? acc.x : 0;
    int v1 = (base + 1 < n) ? acc.y : 0;
    int v2 = (base + 2 < n) ? acc.z : 0;
    int v3 = (base + 3 < n) ? acc.w : 0;
    int lsum = v0 + v1 + v2 + v3;
    s[tid] = lsum;
    __syncthreads();
    for (int off = 1; off < 256; off <<= 1) {
        int t = (tid >= off) ? s[tid - off] : 0;
        __syncthreads();
        s[tid] += t;
        __syncthreads();
    }
    int excl = s[tid] - lsum;
    if (base + 0 < n) out[base + 0] = excl;
    if (base + 1 < n) out[base + 1] = excl + v0;
    if (base + 2 < n) out[base + 2] = excl + v0 + v1;
    if (base + 3 < n) out[base + 3] = excl + v0 + v1 + v2;
    if (tid == 255) bsum[blockIdx.x] = s[255];
}

__global__ void scan2(const int* __restrict__ bsum, int* __restrict__ boff, int nb) {
    __shared__ int s[256];
    int tid = threadIdx.x;
    int v = (tid < nb) ? bsum[tid] : 0;
    s[tid] = v;
    __syncthreads();
    for (int off = 1; off < 256; off <<= 1) {
        int t = (tid >= off) ? s[tid - off] : 0;
        __syncthreads();
        s[tid] += t;
        __syncthreads();
    }
    if (tid < nb) boff[tid] = s[tid] - v;
}

__global__ void scan3(int* __restrict__ rowptr, const int* __restrict__ boff,
                      int n, int total) {
    int i = blockIdx.x * 256 + threadIdx.x;
    if (i < n) rowptr[i] += boff[i >> 10];
    else if (i == n) rowptr[n] = total;
}

// convert partial counts -> absolute col starting offsets (per node, per chunk)
__global__ void cumpart(int* __restrict__ partial, const int* __restrict__ rowptr, int n) {
    int i = blockIdx.x * 256 + threadIdx.x;
    if (i >= n) return;
    int r = i / HWC, ii = i - r * HWC;
    int* base = partial + (size_t)r * HCHC * HWC + ii;
    int run = rowptr[i];
#pragma unroll 8
    for (int k = 0; k < HCHC; ++k) {
        int v = base[(size_t)k * HWC];
        base[(size_t)k * HWC] = run;
        run += v;
    }
}

// atomic-free CSR fill: block (range,chunk), LDS cursors seeded from cumpart offsets
__launch_bounds__(256)
__global__ void fill_hist(const int* __restrict__ src, const int* __restrict__ dst,
                          const int* __restrict__ partial, int* __restrict__ col,
                          int E, int n) {
    __shared__ int cur[HWC];
    const int tid = threadIdx.x;
    const int range = blockIdx.x / HCHC, chunk = blockIdx.x - range * HCHC;
    const int lo = range * HWC;
    const int hi = min(lo + HWC, n);
    const int* pin = partial + ((size_t)range * HCHC + chunk) * HWC;
    for (int i = tid * 4; i < HWC; i += 1024) *(int4*)&cur[i] = *(const int4*)&pin[i];
    __syncthreads();
    int cbeg = ((int)((long long)chunk * E / HCHC)) & ~3;
    int cend = (chunk == HCHC - 1) ? E : (((int)((long long)(chunk + 1) * E / HCHC)) & ~3);
    int aend = cbeg + ((cend - cbeg) & ~3);
    for (int i = cbeg + tid * 4; i + 3 < cend; i += 1024) {
        int4 d = *(const int4*)(dst + i);
        int4 sv = *(const int4*)(src + i);
        if (d.x >= lo && d.x < hi) col[atomicAdd(&cur[d.x - lo], 1)] = sv.x;
        if (d.y >= lo && d.y < hi) col[atomicAdd(&cur[d.y - lo], 1)] = sv.y;
        if (d.z >= lo && d.z < hi) col[atomicAdd(&cur[d.z - lo], 1)] = sv.z;
        if (d.w >= lo && d.w < hi) col[atomicAdd(&cur[d.w - lo], 1)] = sv.w;
    }
    if (tid < cend - aend) {
        int d = dst[aend + tid];
        if (d >= lo && d < hi) col[atomicAdd(&cur[d - lo], 1)] = src[aend + tid];
    }
}

// ---------------- weight prep (all 6 sets in one kernel) ----------------

__device__ void prep_one(const float* __restrict__ Wl, const float* __restrict__ Wr,
                         const float* __restrict__ bl, int K,
                         unsigned short* __restrict__ Wth, unsigned short* __restrict__ Wtl,
                         float* __restrict__ biasOut, int gid, int gsz) {
    int tot = 128 * K;
    for (int idx = gid; idx < tot; idx += gsz) {
        int c = idx / K, k = idx - c * K;
        float wv = (c < 64) ? Wl[(size_t)k * 64 + c] : Wr[(size_t)k * 64 + (c - 64)];
        unsigned short h = f2bf(wv);
        Wth[idx] = h;
        Wtl[idx] = f2bf(wv - bf2f(h));
    }
    for (int idx = gid; idx < 128; idx += gsz)
        biasOut[idx] = (idx < 64) ? 0.f : bl[idx - 64];
}

__global__ void prep_all(const float* __restrict__ m0Wl, const float* __restrict__ m0Wr,
                         const float* __restrict__ m0bl,
                         const float* __restrict__ v0Wl, const float* __restrict__ v0Wr,
                         const float* __restrict__ v0bl,
                         const float* __restrict__ mRWl, const float* __restrict__ mRWr,
                         const float* __restrict__ mRbl,
                         const float* __restrict__ vRWl, const float* __restrict__ vRWr,
                         const float* __restrict__ vRbl,
                         unsigned short* __restrict__ w0h, unsigned short* __restrict__ w0l,
                         unsigned short* __restrict__ wlh, unsigned short* __restrict__ wll,
                         float* __restrict__ biasAll) {
    int gid = blockIdx.x * 256 + threadIdx.x;
    int gsz = gridDim.x * 256;
    prep_one(m0Wl, m0Wr, m0bl, 128, w0h, w0l, biasAll, gid, gsz);
    prep_one(v0Wl, v0Wr, v0bl, 128, w0h + 128 * 128, w0l + 128 * 128, biasAll + 128, gid, gsz);
    for (int i = 0; i < 2; ++i) {
        prep_one(mRWl + (size_t)i * 4096, mRWr + (size_t)i * 4096, mRbl + (size_t)i * 64, 64,
                 wlh + (size_t)(2 * i) * 8192, wll + (size_t)(2 * i) * 8192,
                 biasAll + (2 + 2 * i) * 128, gid, gsz);
        prep_one(vRWl + (size_t)i * 4096, vRWr + (size_t)i * 4096, vRbl + (size_t)i * 64, 64,
                 wlh + (size_t)(2 * i + 1) * 8192, wll + (size_t)(2 * i + 1) * 8192,
                 biasAll + (2 + 2 * i + 1) * 128, gid, gsz);
    }
}

// ---------------- dual-path split-bf16 MFMA GEMM, fp32 A from global ----------------
// Pure GEMM, round-12-proven codegen (A loads inline, VGPR 84).
// Output TLRu[r*128+c] = bf16(mean) | bf16(var)<<16 ; c<64: TL, c>=64: TR(+bias).

__launch_bounds__(256)
__global__ void gemm_dual(const float* __restrict__ Am, const float* __restrict__ Av,
                          const unsigned short* __restrict__ Wh,  // [2][128*Kg]
                          const unsigned short* __restrict__ Wl,  // [2][128*Kg]
                          const float* __restrict__ bias,         // [2][128]
                          unsigned* __restrict__ TLRu, int Kg, int Nn) {
    __shared__ unsigned short Bh[128 * 72], Bl[128 * 72];
    const int tid = threadIdx.x;
    const int l = tid & 63, w = tid >> 6;
    const int rowbase = blockIdx.x * 64;
    const int r = rowbase + w * 16 + (l & 15);
    const bool rok = r < Nn;
    const int kofs = (l >> 4) * 8;
    f32x4 acc[2][8] = {};

    bool first = true;
    for (int k0 = 0; k0 < Kg; k0 += 64) {
#pragma unroll
        for (int p = 0; p < 2; ++p) {
            if (!first) __syncthreads();
            first = false;
            // stage B (one path) into LDS
#pragma unroll
            for (int q = 0; q < 4; ++q) {
                int lin = q * 256 + tid;
                int c = lin >> 3;
                int k8 = (lin & 7) << 3;
                *(short8*)&Bh[c * 72 + k8] =
                    *(const short8*)(Wh + (size_t)p * 128 * Kg + (size_t)c * Kg + k0 + k8);
                *(short8*)&Bl[c * 72 + k8] =
                    *(const short8*)(Wl + (size_t)p * 128 * Kg + (size_t)c * Kg + k0 + k8);
            }
            __syncthreads();
            const float* As = p ? Av : Am;
#pragma unroll
            for (int kk = 0; kk < 64; kk += 32) {
                short8 a_h = {}, a_l = {};
                if (rok) {
                    const float* xr = As + (size_t)r * Kg + k0 + kofs + kk;
                    float4 v0 = *(const float4*)xr;
                    float4 v1 = *(const float4*)(xr + 4);
                    float f[8] = {v0.x, v0.y, v0.z, v0.w, v1.x, v1.y, v1.z, v1.w};
#pragma unroll
                    for (int i = 0; i < 8; ++i) {
                        unsigned short h = f2bf(f[i]);
                        a_h[i] = (short)h;
                        a_l[i] = (short)f2bf(f[i] - bf2f(h));
                    }
                }
#pragma unroll
                for (int ct = 0; ct < 8; ++ct) {
                    const int br = (ct * 16 + (l & 15)) * 72 + kk + kofs;
                    short8 b_h = *(const short8*)&Bh[br];
                    short8 b_l = *(const short8*)&Bl[br];
                    acc[p][ct] = __builtin_amdgcn_mfma_f32_16x16x32_bf16(a_h, b_h, acc[p][ct], 0, 0, 0);
                    acc[p][ct] = __builtin_amdgcn_mfma_f32_16x16x32_bf16(a_h, b_l, acc[p][ct], 0, 0, 0);
                    acc[p][ct] = __builtin_amdgcn_mfma_f32_16x16x32_bf16(a_l, b_h, acc[p][ct], 0, 0, 0);
                }
            }
        }
    }
    const int r0 = rowbase + w * 16 + ((l >> 4) << 2);
#pragma unroll
    for (int ct = 0; ct < 8; ++ct) {
        int c = ct * 16 + (l & 15);
        float b0 = bias[c];
        float b1 = bias[128 + c];
#pragma unroll
        for (int i = 0; i < 4; ++i) {
            int rr = r0 + i;
            if (rr < Nn) {
                unsigned hm = f2bf(acc[0][ct][i] + b0);
                unsigned hv = f2bf(acc[1][ct][i] + b1);
                TLRu[(size_t)rr * 128 + c] = hm | (hv << 16);
            }
        }
    }
}

// ---------------- fused CSR aggregate (mean+var): relu(agg(TL)/deg + TR) ----------------

__launch_bounds__(256)
__global__ void agg_fused(const unsigned* __restrict__ TLRu,
                          const int* __restrict__ rowptr, const int* __restrict__ col,
                          float* __restrict__ outm, float* __restrict__ outv, int n) {
    int node = blockIdx.x * 16 + (threadIdx.x >> 4);
    if (node >= n) return;
    const int sub = threadIdx.x & 15;
    const int s = rowptr[node], e = rowptr[node + 1];
    float4 am0 = {0, 0, 0, 0}, av0 = {0, 0, 0, 0};
    float4 am1 = {0, 0, 0, 0}, av1 = {0, 0, 0, 0};
    int j = s;
    for (; j + 8 <= e; j += 8) {
        int c0 = col[j], c1 = col[j + 1], c2 = col[j + 2], c3 = col[j + 3];
        int c4 = col[j + 4], c5 = col[j + 5], c6 = col[j + 6], c7 = col[j + 7];
        uint4 u0 = ((const uint4*)(TLRu + (size_t)c0 * 128))[sub];
        uint4 u1 = ((const uint4*)(TLRu + (size_t)c1 * 128))[sub];
        uint4 u2 = ((const uint4*)(TLRu + (size_t)c2 * 128))[sub];
        uint4 u3 = ((const uint4*)(TLRu + (size_t)c3 * 128))[sub];
        uint4 u4 = ((const uint4*)(TLRu + (size_t)c4 * 128))[sub];
        uint4 u5 = ((const uint4*)(TLRu + (size_t)c5 * 128))[sub];
        uint4 u6 = ((const uint4*)(TLRu + (size_t)c6 * 128))[sub];
        uint4 u7 = ((const uint4*)(TLRu + (size_t)c7 * 128))[sub];
        acc_u4(u0, am0, av0);
        acc_u4(u1, am1, av1);
        acc_u4(u2, am0, av0);
        acc_u4(u3, am1, av1);
        acc_u4(u4, am0, av0);
        acc_u4(u5, am1, av1);
        acc_u4(u6, am0, av0);
        acc_u4(u7, am1, av1);
    }
    if (j + 4 <= e) {
        int c0 = col[j], c1 = col[j + 1], c2 = col[j + 2], c3 = col[j + 3];
        uint4 u0 = ((const uint4*)(TLRu + (size_t)c0 * 128))[sub];
        uint4 u1 = ((const uint4*)(TLRu + (size_t)c1 * 128))[sub];
        uint4 u2 = ((const uint4*)(TLRu + (size_t)c2 * 128))[sub];
        uint4 u3 = ((const uint4*)(TLRu + (size_t)c3 * 128))[sub];
        acc_u4(u0, am0, av0);
        acc_u4(u1, am1, av1);
        acc_u4(u2, am0, av0);
        acc_u4(u3, am1, av1);
        j += 4;
    }
    for (; j < e; ++j) {
        int c0 = col[j];
        uint4 u0 = ((const uint4*)(TLRu + (size_t)c0 * 128))[sub];
        acc_u4(u0, am0, av0);
    }
    am0.x += am1.x; am0.y += am1.y; am0.z += am1.z; am0.w += am1.w;
    av0.x += av1.x; av0.y += av1.y; av0.z += av1.z; av0.w += av1.w;

    float inv = 1.0f / (float)max(e - s, 1);
    uint4 t = ((const uint4*)(TLRu + (size_t)node * 128 + 64))[sub];
    float vm0 = fmaxf(fmaf(am0.x, inv, bf2f_u(t.x & 0xffff)), 0.f);
    float vv0 = fmaxf(fmaf(av0.x, inv, __uint_as_float(t.x & 0xffff0000u)), 0.f);
    float vm1 = fmaxf(fmaf(am0.y, inv, bf2f_u(t.y & 0xffff)), 0.f);
    float vv1 = fmaxf(fmaf(av0.y, inv, __uint_as_float(t.y & 0xffff0000u)), 0.f);
    float vm2 = fmaxf(fmaf(am0.z, inv, bf2f_u(t.z & 0xffff)), 0.f);
    float vv2 = fmaxf(fmaf(av0.z, inv, __uint_as_float(t.z & 0xffff0000u)), 0.f);
    float vm3 = fmaxf(fmaf(am0.w, inv, bf2f_u(t.w & 0xffff)), 0.f);
    float vv3 = fmaxf(fmaf(av0.w, inv, __uint_as_float(t.w & 0xffff0000u)), 0.f);
    size_t o = (size_t)node * 64 + sub * 4;
    *(float4*)(outm + o) = make_float4(vm0, vm1, vm2, vm3);
    *(float4*)(outv + o) = make_float4(vv0, vv1, vv2, vv3);
}

// ---------------- per-group: reparam + mean-pool + fc1 + relu + fc2 + log_softmax ----------------

__launch_bounds__(256)
__global__ void pool_head(const float* __restrict__ mean, const float* __restrict__ logv,
                          const float* __restrict__ eps, const int* __restrict__ batch,
                          const float* __restrict__ fc1W, const float* __restrict__ fc1b,
                          const float* __restrict__ fc2W, const float* __restrict__ fc2b,
                          float* __restrict__ out, int n) {
    __shared__ int se[2];
    __shared__ float4 red[256];
    __shared__ float pooled[64];
    __shared__ float hbuf[128];
    __shared__ float lg[2];
    const int g = blockIdx.x, tid = threadIdx.x;
    if (tid == 0 || tid == 64) {
        int key = g + (tid >> 6);
        int a = 0, b = n;
        while (a < b) {
            int m = (a + b) >> 1;
            if (batch[m] < key) a = m + 1;
            else b = m;
        }
        se[tid >> 6] = a;
    }
    __syncthreads();
    const int s = se[0], e = se[1];
    const int nof = tid >> 4, fq = tid & 15;
    float4 acc = make_float4(0.f, 0.f, 0.f, 0.f);
    for (int i = s + nof; i < e; i += 16) {
        size_t o = (size_t)i * 64 + fq * 4;
        float4 m4 = *(const float4*)(mean + o);
        float4 l4 = *(const float4*)(logv + o);
        float4 e4 = *(const float4*)(eps + o);
        acc.x += m4.x + e4.x * expf(0.5f * l4.x);
        acc.y += m4.y + e4.y * expf(0.5f * l4.y);
        acc.z += m4.z + e4.z * expf(0.5f * l4.z);
        acc.w += m4.w + e4.w * expf(0.5f * l4.w);
    }
    red[tid] = acc;
    __syncthreads();
    if (tid < 16) {
        float4 sum = red[fq];
        for (int j = 1; j < 16; ++j) {
            float4 r = red[j * 16 + fq];
            sum.x += r.x;
            sum.y += r.y;
            sum.z += r.z;
            sum.w += r.w;
        }
        float inv = 1.0f / (float)max(e - s, 1);
        pooled[fq * 4 + 0] = sum.x * inv;
        pooled[fq * 4 + 1] = sum.y * inv;
        pooled[fq * 4 + 2] = sum.z * inv;
        pooled[fq * 4 + 3] = sum.w * inv;
    }
    __syncthreads();
    if (tid < 128) {
        float a = fc1b[tid];
        for (int k = 0; k < 64; ++k) a = fmaf(pooled[k], fc1W[k * 128 + tid], a);
        hbuf[tid] = fmaxf(a, 0.f);
    }
    __syncthreads();
    if (tid < 2) {
        float a = fc2b[tid];
        for (int k = 0; k < 128; ++k) a = fmaf(hbuf[k], fc2W[k * 2 + tid], a);
        lg[tid] = a;
    }
    __syncthreads();
    if (tid < 2) {
        float m = fmaxf(lg[0], lg[1]);
        float lse = m + logf(expf(lg[0] - m) + expf(lg[1] - m));
        out[(size_t)g * 2 + tid] = lg[tid] - lse;
    }
}

extern "C" void kernel_launch(void* const* d_in, const int* in_sizes, int n_in,
                              void* d_out, int out_size, void* d_ws, size_t ws_size,
                              hipStream_t stream) {
    const int N = in_sizes[19];
    const int E = in_sizes[18] / 2;
    const int G = (out_size - 2 * N * NH) / NCLS;

    const float* x    = (const float*)d_in[0];
    const float* eps  = (const float*)d_in[1];
    const float* m0Wl = (const float*)d_in[2];
    const float* m0bl = (const float*)d_in[3];
    const float* m0Wr = (const float*)d_in[4];
    const float* mRWl = (const float*)d_in[5];
    const float* mRbl = (const float*)d_in[6];
    const float* mRWr = (const float*)d_in[7];
    const float* v0Wl = (const float*)d_in[8];
    const float* v0bl = (const float*)d_in[9];
    const float* v0Wr = (const float*)d_in[10];
    const float* vRWl = (const float*)d_in[11];
    const float* vRbl = (const float*)d_in[12];
    const float* vRWr = (const float*)d_in[13];
    const float* fc1W = (const float*)d_in[14];
    const float* fc1b = (const float*)d_in[15];
    const float* fc2W = (const float*)d_in[16];
    const float* fc2b = (const float*)d_in[17];
    const int* eidx   = (const int*)d_in[18];
    const int* batch  = (const int*)d_in[19];
    const int* srcI = eidx;
    const int* dstI = eidx + E;

    float* out_ls = (float*)d_out;
    float* out_mean = out_ls + (size_t)G * NCLS;
    float* out_lv = out_mean + (size_t)N * NH;

    char* w = (char*)d_ws;
    auto alloc = [&](size_t bytes) {
        char* p = w;
        w += (bytes + 255) & ~(size_t)255;
        return p;
    };
    int* rowptr = (int*)alloc((size_t)(N + 1) * 4);
    int* bsum = (int*)alloc(256 * 4);
    int* boff = (int*)alloc(256 * 4);
    int* col = (int*)alloc((size_t)E * 4);
    unsigned* TLRu = (unsigned*)alloc((size_t)N * 128 * 4);  // packed mean|var (also hist scratch)
    unsigned short* w0h = (unsigned short*)alloc(2 * 128 * 128 * 2);
    unsigned short* w0l = (unsigned short*)alloc(2 * 128 * 128 * 2);
    unsigned short* wlh = (unsigned short*)alloc(4 * 128 * 64 * 2);
    unsigned short* wll = (unsigned short*)alloc(4 * 128 * 64 * 2);
    float* biasAll = (float*)alloc(6 * 128 * 4);
    (void)n_in;

    // fp32 inter-layer state: prefer workspace; fall back to d_out placement.
    float* Sm;
    float* Sv;
    size_t used = (size_t)(w - (char*)d_ws);
    if (used + 2 * ((size_t)N * NH * 4 + 256) <= ws_size) {
        Sm = (float*)alloc((size_t)N * NH * 4);
        Sv = (float*)alloc((size_t)N * NH * 4);
    } else {
        Sm = out_mean;
        Sv = out_lv;
    }

    const int nbScan = (N + 1023) / 1024;
    const int nbR = (N + 63) / 64;
    const int nbAgg = (N + 15) / 16;
    const int nRange = (N + HWC - 1) / HWC;

    // weight prep
    prep_all<<<128, 256, 0, stream>>>(m0Wl, m0Wr, m0bl, v0Wl, v0Wr, v0bl,
                                      mRWl, mRWr, mRbl, vRWl, vRWr, vRbl,
                                      w0h, w0l, wlh, wll, biasAll);

    // CSR build: histogram -> rowptr -> cumulative offsets -> atomic-free fill
    int* partial = (int*)TLRu;  // scratch; fully consumed before gemm0 overwrites
    count_hist<<<nRange * HCHC, 256, 0, stream>>>(dstI, partial, E, N);
    scan1p<<<nbScan, 256, 0, stream>>>(partial, rowptr, bsum, N);
    scan2<<<1, 256, 0, stream>>>(bsum, boff, nbScan);
    scan3<<<(N + 256) / 256 + 1, 256, 0, stream>>>(rowptr, boff, N, E);
    cumpart<<<(N + 255) / 256, 256, 0, stream>>>(partial, rowptr, N);
    fill_hist<<<nRange * HCHC, 256, 0, stream>>>(srcI, dstI, partial, col, E, N);

    // layer-0 GEMM (overwrites TLRu after fill consumed the partials)
    gemm_dual<<<nbR, 256, 0, stream>>>(x, x, w0h, w0l, biasAll, TLRu, 128, N);
    agg_fused<<<nbAgg, 256, 0, stream>>>(TLRu, rowptr, col, Sm, Sv, N);

    // layers 1..2 (K=64, fp32 state)
    for (int i = 0; i < 2; ++i) {
        const bool fin = (i == 1);
        gemm_dual<<<nbR, 256, 0, stream>>>(Sm, Sv,
                                           wlh + (size_t)(2 * i) * 8192,
                                           wll + (size_t)(2 * i) * 8192,
                                           biasAll + (2 + 2 * i) * 128, TLRu, 64, N);
        if (fin)
            agg_fused<<<nbAgg, 256, 0, stream>>>(TLRu, rowptr, col, out_mean, out_lv, N);
        else
            agg_fused<<<nbAgg, 256, 0, stream>>>(TLRu, rowptr, col, Sm, Sv, N);
    }

    // reparam + pool + FC head, one block per graph
    pool_head<<<G, 256, 0, stream>>>(out_mean, out_lv, eps, batch, fc1W, fc1b, fc2W, fc2b,
                                     out_ls, N);
}

// Round 15
// 436.748 us; speedup vs baseline: 1.1503x; 1.0415x over previous
//
#include <hip/hip_runtime.h>

#define NH 64
#define NCLS 2
#define HWC 32768  // histogram window (nodes per range), 128KB LDS
#define HCHC 32    // edge chunks per range

typedef short short8 __attribute__((ext_vector_type(8)));
typedef float f32x4 __attribute__((ext_vector_type(4)));

__device__ inline unsigned short f2bf(float x) {
    unsigned u = __float_as_uint(x);
    unsigned r = (u + 0x7FFFu + ((u >> 16) & 1u)) >> 16;
    return (unsigned short)r;
}
__device__ inline float bf2f(unsigned short h) { return __uint_as_float(((unsigned)h) << 16); }
__device__ inline float bf2f_u(unsigned h) { return __uint_as_float(h << 16); }

__device__ inline void acc_u4(uint4 u, float4& am, float4& av) {
    am.x += __uint_as_float(u.x << 16);
    av.x += __uint_as_float(u.x & 0xffff0000u);
    am.y += __uint_as_float(u.y << 16);
    av.y += __uint_as_float(u.y & 0xffff0000u);
    am.z += __uint_as_float(u.z << 16);
    av.z += __uint_as_float(u.z & 0xffff0000u);
    am.w += __uint_as_float(u.w << 16);
    av.w += __uint_as_float(u.w & 0xffff0000u);
}

// ---------------- degree count: atomic-free two-level histogram ----------------

__launch_bounds__(256)
__global__ void count_hist(const int* __restrict__ dst, int* __restrict__ partial,
                           int E, int n) {
    __shared__ int hist[HWC];
    const int tid = threadIdx.x;
    const int range = blockIdx.x / HCHC, chunk = blockIdx.x - range * HCHC;
    const int lo = range * HWC;
    const int hi = min(lo + HWC, n);
    for (int i = tid * 4; i < HWC; i += 1024) *(int4*)&hist[i] = make_int4(0, 0, 0, 0);
    __syncthreads();
    int cbeg = ((int)((long long)chunk * E / HCHC)) & ~3;
    int cend = (chunk == HCHC - 1) ? E : (((int)((long long)(chunk + 1) * E / HCHC)) & ~3);
    int aend = cbeg + ((cend - cbeg) & ~3);
    for (int i = cbeg + tid * 4; i + 3 < cend; i += 1024) {
        int4 d = *(const int4*)(dst + i);
        if (d.x >= lo && d.x < hi) atomicAdd(&hist[d.x - lo], 1);
        if (d.y >= lo && d.y < hi) atomicAdd(&hist[d.y - lo], 1);
        if (d.z >= lo && d.z < hi) atomicAdd(&hist[d.z - lo], 1);
        if (d.w >= lo && d.w < hi) atomicAdd(&hist[d.w - lo], 1);
    }
    if (tid < cend - aend) {
        int d = dst[aend + tid];
        if (d >= lo && d < hi) atomicAdd(&hist[d - lo], 1);
    }
    __syncthreads();
    int* pout = partial + ((size_t)range * HCHC + chunk) * HWC;
    for (int i = tid * 4; i < HWC; i += 1024) *(int4*)&pout[i] = *(const int4*)&hist[i];
}

// block exclusive scan over deg (deg computed on the fly from the partials)
__global__ void scan1p(const int* __restrict__ partial, int* __restrict__ out,
                       int* __restrict__ bsum, int n) {
    __shared__ int s[256];
    int tid = threadIdx.x;
    int base = blockIdx.x * 1024 + tid * 4;
    int4 acc = make_int4(0, 0, 0, 0);
    if (base < n) {
        int r = base / HWC;
        int ii = base - r * HWC;
        const int* pr = partial + (size_t)r * HCHC * HWC + ii;
#pragma unroll 8
        for (int k = 0; k < HCHC; ++k) {
            int4 v = *(const int4*)(pr + (size_t)k * HWC);
            acc.x += v.x;
            acc.y += v.y;
            acc.z += v.z;
            acc.w += v.w;
        }
    }
    int v0 = (base + 0 < n) ? acc.x : 0;
    int v1 = (base + 1 < n) ? acc.y : 0;
    int v2 = (base + 2 < n) ? acc.z : 0;
    int v3 = (base + 3 < n) ? acc.w : 0;
    int lsum = v0 + v1 + v2 + v3;
    s[tid] = lsum;
    __syncthreads();
    for (int off = 1; off < 256; off <<= 1) {
        int t = (tid >= off) ? s[tid - off] : 0;
        __syncthreads();
        s[tid] += t;
        __syncthreads();
    }
    int excl = s[tid] - lsum;
    if (base + 0 < n) out[base + 0] = excl;
    if (base + 1 < n) out[base + 1] = excl + v0;
    if (base + 2 < n) out[base + 2] = excl + v0 + v1;
    if (base + 3 < n) out[base + 3] = excl + v0 + v1 + v2;
    if (tid == 255) bsum[blockIdx.x] = s[255];
}

__global__ void scan2(const int* __restrict__ bsum, int* __restrict__ boff, int nb) {
    __shared__ int s[256];
    int tid = threadIdx.x;
    int v = (tid < nb) ? bsum[tid] : 0;
    s[tid] = v;
    __syncthreads();
    for (int off = 1; off < 256; off <<= 1) {
        int t = (tid >= off) ? s[tid - off] : 0;
        __syncthreads();
        s[tid] += t;
        __syncthreads();
    }
    if (tid < nb) boff[tid] = s[tid] - v;
}

__global__ void scan3(int* __restrict__ rowptr, const int* __restrict__ boff,
                      int n, int total) {
    int i = blockIdx.x * 256 + threadIdx.x;
    if (i < n) rowptr[i] += boff[i >> 10];
    else if (i == n) rowptr[n] = total;
}

// convert partial counts -> absolute col starting offsets (per node, per chunk)
__global__ void cumpart(int* __restrict__ partial, const int* __restrict__ rowptr, int n) {
    int i = blockIdx.x * 256 + threadIdx.x;
    if (i >= n) return;
    int r = i / HWC, ii = i - r * HWC;
    int* base = partial + (size_t)r * HCHC * HWC + ii;
    int run = rowptr[i];
#pragma unroll 8
    for (int k = 0; k < HCHC; ++k) {
        int v = base[(size_t)k * HWC];
        base[(size_t)k * HWC] = run;
        run += v;
    }
}

// atomic-free CSR fill: block (range,chunk), LDS cursors seeded from cumpart offsets.
// XCD-aware remap: all chunk-blocks of one range share an XCD -> the range's col
// write window (~1.6MB) stays resident in that XCD's L2, killing line-RMW amp.
__launch_bounds__(256)
__global__ void fill_hist(const int* __restrict__ src, const int* __restrict__ dst,
                          const int* __restrict__ partial, int* __restrict__ col,
                          int E, int n) {
    __shared__ int cur[HWC];
    const int tid = threadIdx.x;
    int s0 = blockIdx.x;
    const int total = gridDim.x;
    if ((total & 7) == 0) {
        int per = total >> 3;
        s0 = (blockIdx.x & 7) * per + (blockIdx.x >> 3);
    }
    const int range = s0 / HCHC, chunk = s0 - range * HCHC;
    const int lo = range * HWC;
    const int hi = min(lo + HWC, n);
    const int* pin = partial + ((size_t)range * HCHC + chunk) * HWC;
    for (int i = tid * 4; i < HWC; i += 1024) *(int4*)&cur[i] = *(const int4*)&pin[i];
    __syncthreads();
    int cbeg = ((int)((long long)chunk * E / HCHC)) & ~3;
    int cend = (chunk == HCHC - 1) ? E : (((int)((long long)(chunk + 1) * E / HCHC)) & ~3);
    int aend = cbeg + ((cend - cbeg) & ~3);
    for (int i = cbeg + tid * 4; i + 3 < cend; i += 1024) {
        int4 d = *(const int4*)(dst + i);
        int4 sv = *(const int4*)(src + i);
        if (d.x >= lo && d.x < hi) col[atomicAdd(&cur[d.x - lo], 1)] = sv.x;
        if (d.y >= lo && d.y < hi) col[atomicAdd(&cur[d.y - lo], 1)] = sv.y;
        if (d.z >= lo && d.z < hi) col[atomicAdd(&cur[d.z - lo], 1)] = sv.z;
        if (d.w >= lo && d.w < hi) col[atomicAdd(&cur[d.w - lo], 1)] = sv.w;
    }
    if (tid < cend - aend) {
        int d = dst[aend + tid];
        if (d >= lo && d < hi) col[atomicAdd(&cur[d - lo], 1)] = src[aend + tid];
    }
}

// ---------------- weight prep (all 6 sets in one kernel) ----------------

__device__ void prep_one(const float* __restrict__ Wl, const float* __restrict__ Wr,
                         const float* __restrict__ bl, int K,
                         unsigned short* __restrict__ Wth, unsigned short* __restrict__ Wtl,
                         float* __restrict__ biasOut, int gid, int gsz) {
    int tot = 128 * K;
    for (int idx = gid; idx < tot; idx += gsz) {
        int c = idx / K, k = idx - c * K;
        float wv = (c < 64) ? Wl[(size_t)k * 64 + c] : Wr[(size_t)k * 64 + (c - 64)];
        unsigned short h = f2bf(wv);
        Wth[idx] = h;
        Wtl[idx] = f2bf(wv - bf2f(h));
    }
    for (int idx = gid; idx < 128; idx += gsz)
        biasOut[idx] = (idx < 64) ? 0.f : bl[idx - 64];
}

__global__ void prep_all(const float* __restrict__ m0Wl, const float* __restrict__ m0Wr,
                         const float* __restrict__ m0bl,
                         const float* __restrict__ v0Wl, const float* __restrict__ v0Wr,
                         const float* __restrict__ v0bl,
                         const float* __restrict__ mRWl, const float* __restrict__ mRWr,
                         const float* __restrict__ mRbl,
                         const float* __restrict__ vRWl, const float* __restrict__ vRWr,
                         const float* __restrict__ vRbl,
                         unsigned short* __restrict__ w0h, unsigned short* __restrict__ w0l,
                         unsigned short* __restrict__ wlh, unsigned short* __restrict__ wll,
                         float* __restrict__ biasAll) {
    int gid = blockIdx.x * 256 + threadIdx.x;
    int gsz = gridDim.x * 256;
    prep_one(m0Wl, m0Wr, m0bl, 128, w0h, w0l, biasAll, gid, gsz);
    prep_one(v0Wl, v0Wr, v0bl, 128, w0h + 128 * 128, w0l + 128 * 128, biasAll + 128, gid, gsz);
    for (int i = 0; i < 2; ++i) {
        prep_one(mRWl + (size_t)i * 4096, mRWr + (size_t)i * 4096, mRbl + (size_t)i * 64, 64,
                 wlh + (size_t)(2 * i) * 8192, wll + (size_t)(2 * i) * 8192,
                 biasAll + (2 + 2 * i) * 128, gid, gsz);
        prep_one(vRWl + (size_t)i * 4096, vRWr + (size_t)i * 4096, vRbl + (size_t)i * 64, 64,
                 wlh + (size_t)(2 * i + 1) * 8192, wll + (size_t)(2 * i + 1) * 8192,
                 biasAll + (2 + 2 * i + 1) * 128, gid, gsz);
    }
}

// ---------------- dual-path split-bf16 MFMA GEMM, fp32 A from global ----------------
// Pure GEMM, round-12-proven codegen (A loads inline, VGPR 84).
// Output TLRu[r*128+c] = bf16(mean) | bf16(var)<<16 ; c<64: TL, c>=64: TR(+bias).

__launch_bounds__(256)
__global__ void gemm_dual(const float* __restrict__ Am, const float* __restrict__ Av,
                          const unsigned short* __restrict__ Wh,  // [2][128*Kg]
                          const unsigned short* __restrict__ Wl,  // [2][128*Kg]
                          const float* __restrict__ bias,         // [2][128]
                          unsigned* __restrict__ TLRu, int Kg, int Nn) {
    __shared__ unsigned short Bh[128 * 72], Bl[128 * 72];
    const int tid = threadIdx.x;
    const int l = tid & 63, w = tid >> 6;
    const int rowbase = blockIdx.x * 64;
    const int r = rowbase + w * 16 + (l & 15);
    const bool rok = r < Nn;
    const int kofs = (l >> 4) * 8;
    f32x4 acc[2][8] = {};

    bool first = true;
    for (int k0 = 0; k0 < Kg; k0 += 64) {
#pragma unroll
        for (int p = 0; p < 2; ++p) {
            if (!first) __syncthreads();
            first = false;
            // stage B (one path) into LDS
#pragma unroll
            for (int q = 0; q < 4; ++q) {
                int lin = q * 256 + tid;
                int c = lin >> 3;
                int k8 = (lin & 7) << 3;
                *(short8*)&Bh[c * 72 + k8] =
                    *(const short8*)(Wh + (size_t)p * 128 * Kg + (size_t)c * Kg + k0 + k8);
                *(short8*)&Bl[c * 72 + k8] =
                    *(const short8*)(Wl + (size_t)p * 128 * Kg + (size_t)c * Kg + k0 + k8);
            }
            __syncthreads();
            const float* As = p ? Av : Am;
#pragma unroll
            for (int kk = 0; kk < 64; kk += 32) {
                short8 a_h = {}, a_l = {};
                if (rok) {
                    const float* xr = As + (size_t)r * Kg + k0 + kofs + kk;
                    float4 v0 = *(const float4*)xr;
                    float4 v1 = *(const float4*)(xr + 4);
                    float f[8] = {v0.x, v0.y, v0.z, v0.w, v1.x, v1.y, v1.z, v1.w};
#pragma unroll
                    for (int i = 0; i < 8; ++i) {
                        unsigned short h = f2bf(f[i]);
                        a_h[i] = (short)h;
                        a_l[i] = (short)f2bf(f[i] - bf2f(h));
                    }
                }
#pragma unroll
                for (int ct = 0; ct < 8; ++ct) {
                    const int br = (ct * 16 + (l & 15)) * 72 + kk + kofs;
                    short8 b_h = *(const short8*)&Bh[br];
                    short8 b_l = *(const short8*)&Bl[br];
                    acc[p][ct] = __builtin_amdgcn_mfma_f32_16x16x32_bf16(a_h, b_h, acc[p][ct], 0, 0, 0);
                    acc[p][ct] = __builtin_amdgcn_mfma_f32_16x16x32_bf16(a_h, b_l, acc[p][ct], 0, 0, 0);
                    acc[p][ct] = __builtin_amdgcn_mfma_f32_16x16x32_bf16(a_l, b_h, acc[p][ct], 0, 0, 0);
                }
            }
        }
    }
    const int r0 = rowbase + w * 16 + ((l >> 4) << 2);
#pragma unroll
    for (int ct = 0; ct < 8; ++ct) {
        int c = ct * 16 + (l & 15);
        float b0 = bias[c];
        float b1 = bias[128 + c];
#pragma unroll
        for (int i = 0; i < 4; ++i) {
            int rr = r0 + i;
            if (rr < Nn) {
                unsigned hm = f2bf(acc[0][ct][i] + b0);
                unsigned hv = f2bf(acc[1][ct][i] + b1);
                TLRu[(size_t)rr * 128 + c] = hm | (hv << 16);
            }
        }
    }
}

// ---------------- fused CSR aggregate (mean+var): relu(agg(TL)/deg + TR) ----------------

__launch_bounds__(256)
__global__ void agg_fused(const unsigned* __restrict__ TLRu,
                          const int* __restrict__ rowptr, const int* __restrict__ col,
                          float* __restrict__ outm, float* __restrict__ outv, int n) {
    int node = blockIdx.x * 16 + (threadIdx.x >> 4);
    if (node >= n) return;
    const int sub = threadIdx.x & 15;
    const int s = rowptr[node], e = rowptr[node + 1];
    float4 am0 = {0, 0, 0, 0}, av0 = {0, 0, 0, 0};
    float4 am1 = {0, 0, 0, 0}, av1 = {0, 0, 0, 0};
    int j = s;
    for (; j + 8 <= e; j += 8) {
        int c0 = col[j], c1 = col[j + 1], c2 = col[j + 2], c3 = col[j + 3];
        int c4 = col[j + 4], c5 = col[j + 5], c6 = col[j + 6], c7 = col[j + 7];
        uint4 u0 = ((const uint4*)(TLRu + (size_t)c0 * 128))[sub];
        uint4 u1 = ((const uint4*)(TLRu + (size_t)c1 * 128))[sub];
        uint4 u2 = ((const uint4*)(TLRu + (size_t)c2 * 128))[sub];
        uint4 u3 = ((const uint4*)(TLRu + (size_t)c3 * 128))[sub];
        uint4 u4 = ((const uint4*)(TLRu + (size_t)c4 * 128))[sub];
        uint4 u5 = ((const uint4*)(TLRu + (size_t)c5 * 128))[sub];
        uint4 u6 = ((const uint4*)(TLRu + (size_t)c6 * 128))[sub];
        uint4 u7 = ((const uint4*)(TLRu + (size_t)c7 * 128))[sub];
        acc_u4(u0, am0, av0);
        acc_u4(u1, am1, av1);
        acc_u4(u2, am0, av0);
        acc_u4(u3, am1, av1);
        acc_u4(u4, am0, av0);
        acc_u4(u5, am1, av1);
        acc_u4(u6, am0, av0);
        acc_u4(u7, am1, av1);
    }
    if (j + 4 <= e) {
        int c0 = col[j], c1 = col[j + 1], c2 = col[j + 2], c3 = col[j + 3];
        uint4 u0 = ((const uint4*)(TLRu + (size_t)c0 * 128))[sub];
        uint4 u1 = ((const uint4*)(TLRu + (size_t)c1 * 128))[sub];
        uint4 u2 = ((const uint4*)(TLRu + (size_t)c2 * 128))[sub];
        uint4 u3 = ((const uint4*)(TLRu + (size_t)c3 * 128))[sub];
        acc_u4(u0, am0, av0);
        acc_u4(u1, am1, av1);
        acc_u4(u2, am0, av0);
        acc_u4(u3, am1, av1);
        j += 4;
    }
    for (; j < e; ++j) {
        int c0 = col[j];
        uint4 u0 = ((const uint4*)(TLRu + (size_t)c0 * 128))[sub];
        acc_u4(u0, am0, av0);
    }
    am0.x += am1.x; am0.y += am1.y; am0.z += am1.z; am0.w += am1.w;
    av0.x += av1.x; av0.y += av1.y; av0.z += av1.z; av0.w += av1.w;

    float inv = 1.0f / (float)max(e - s, 1);
    uint4 t = ((const uint4*)(TLRu + (size_t)node * 128 + 64))[sub];
    float vm0 = fmaxf(fmaf(am0.x, inv, bf2f_u(t.x & 0xffff)), 0.f);
    float vv0 = fmaxf(fmaf(av0.x, inv, __uint_as_float(t.x & 0xffff0000u)), 0.f);
    float vm1 = fmaxf(fmaf(am0.y, inv, bf2f_u(t.y & 0xffff)), 0.f);
    float vv1 = fmaxf(fmaf(av0.y, inv, __uint_as_float(t.y & 0xffff0000u)), 0.f);
    float vm2 = fmaxf(fmaf(am0.z, inv, bf2f_u(t.z & 0xffff)), 0.f);
    float vv2 = fmaxf(fmaf(av0.z, inv, __uint_as_float(t.z & 0xffff0000u)), 0.f);
    float vm3 = fmaxf(fmaf(am0.w, inv, bf2f_u(t.w & 0xffff)), 0.f);
    float vv3 = fmaxf(fmaf(av0.w, inv, __uint_as_float(t.w & 0xffff0000u)), 0.f);
    size_t o = (size_t)node * 64 + sub * 4;
    *(float4*)(outm + o) = make_float4(vm0, vm1, vm2, vm3);
    *(float4*)(outv + o) = make_float4(vv0, vv1, vv2, vv3);
}

// ---------------- per-group: reparam + mean-pool + fc1 + relu + fc2 + log_softmax ----------------

__launch_bounds__(256)
__global__ void pool_head(const float* __restrict__ mean, const float* __restrict__ logv,
                          const float* __restrict__ eps, const int* __restrict__ batch,
                          const float* __restrict__ fc1W, const float* __restrict__ fc1b,
                          const float* __restrict__ fc2W, const float* __restrict__ fc2b,
                          float* __restrict__ out, int n) {
    __shared__ int se[2];
    __shared__ float4 red[256];
    __shared__ float pooled[64];
    __shared__ float hbuf[128];
    __shared__ float lg[2];
    const int g = blockIdx.x, tid = threadIdx.x;
    if (tid == 0 || tid == 64) {
        int key = g + (tid >> 6);
        int a = 0, b = n;
        while (a < b) {
            int m = (a + b) >> 1;
            if (batch[m] < key) a = m + 1;
            else b = m;
        }
        se[tid >> 6] = a;
    }
    __syncthreads();
    const int s = se[0], e = se[1];
    const int nof = tid >> 4, fq = tid & 15;
    float4 acc = make_float4(0.f, 0.f, 0.f, 0.f);
    for (int i = s + nof; i < e; i += 16) {
        size_t o = (size_t)i * 64 + fq * 4;
        float4 m4 = *(const float4*)(mean + o);
        float4 l4 = *(const float4*)(logv + o);
        float4 e4 = *(const float4*)(eps + o);
        acc.x += m4.x + e4.x * expf(0.5f * l4.x);
        acc.y += m4.y + e4.y * expf(0.5f * l4.y);
        acc.z += m4.z + e4.z * expf(0.5f * l4.z);
        acc.w += m4.w + e4.w * expf(0.5f * l4.w);
    }
    red[tid] = acc;
    __syncthreads();
    if (tid < 16) {
        float4 sum = red[fq];
        for (int j = 1; j < 16; ++j) {
            float4 r = red[j * 16 + fq];
            sum.x += r.x;
            sum.y += r.y;
            sum.z += r.z;
            sum.w += r.w;
        }
        float inv = 1.0f / (float)max(e - s, 1);
        pooled[fq * 4 + 0] = sum.x * inv;
        pooled[fq * 4 + 1] = sum.y * inv;
        pooled[fq * 4 + 2] = sum.z * inv;
        pooled[fq * 4 + 3] = sum.w * inv;
    }
    __syncthreads();
    if (tid < 128) {
        float a = fc1b[tid];
        for (int k = 0; k < 64; ++k) a = fmaf(pooled[k], fc1W[k * 128 + tid], a);
        hbuf[tid] = fmaxf(a, 0.f);
    }
    __syncthreads();
    if (tid < 2) {
        float a = fc2b[tid];
        for (int k = 0; k < 128; ++k) a = fmaf(hbuf[k], fc2W[k * 2 + tid], a);
        lg[tid] = a;
    }
    __syncthreads();
    if (tid < 2) {
        float m = fmaxf(lg[0], lg[1]);
        float lse = m + logf(expf(lg[0] - m) + expf(lg[1] - m));
        out[(size_t)g * 2 + tid] = lg[tid] - lse;
    }
}

extern "C" void kernel_launch(void* const* d_in, const int* in_sizes, int n_in,
                              void* d_out, int out_size, void* d_ws, size_t ws_size,
                              hipStream_t stream) {
    const int N = in_sizes[19];
    const int E = in_sizes[18] / 2;
    const int G = (out_size - 2 * N * NH) / NCLS;

    const float* x    = (const float*)d_in[0];
    const float* eps  = (const float*)d_in[1];
    const float* m0Wl = (const float*)d_in[2];
    const float* m0bl = (const float*)d_in[3];
    const float* m0Wr = (const float*)d_in[4];
    const float* mRWl = (const float*)d_in[5];
    const float* mRbl = (const float*)d_in[6];
    const float* mRWr = (const float*)d_in[7];
    const float* v0Wl = (const float*)d_in[8];
    const float* v0bl = (const float*)d_in[9];
    const float* v0Wr = (const float*)d_in[10];
    const float* vRWl = (const float*)d_in[11];
    const float* vRbl = (const float*)d_in[12];
    const float* vRWr = (const float*)d_in[13];
    const float* fc1W = (const float*)d_in[14];
    const float* fc1b = (const float*)d_in[15];
    const float* fc2W = (const float*)d_in[16];
    const float* fc2b = (const float*)d_in[17];
    const int* eidx   = (const int*)d_in[18];
    const int* batch  = (const int*)d_in[19];
    const int* srcI = eidx;
    const int* dstI = eidx + E;

    float* out_ls = (float*)d_out;
    float* out_mean = out_ls + (size_t)G * NCLS;
    float* out_lv = out_mean + (size_t)N * NH;

    char* w = (char*)d_ws;
    auto alloc = [&](size_t bytes) {
        char* p = w;
        w += (bytes + 255) & ~(size_t)255;
        return p;
    };
    int* rowptr = (int*)alloc((size_t)(N + 1) * 4);
    int* bsum = (int*)alloc(256 * 4);
    int* boff = (int*)alloc(256 * 4);
    int* col = (int*)alloc((size_t)E * 4);
    unsigned* TLRu = (unsigned*)alloc((size_t)N * 128 * 4);  // packed mean|var (also hist scratch)
    unsigned short* w0h = (unsigned short*)alloc(2 * 128 * 128 * 2);
    unsigned short* w0l = (unsigned short*)alloc(2 * 128 * 128 * 2);
    unsigned short* wlh = (unsigned short*)alloc(4 * 128 * 64 * 2);
    unsigned short* wll = (unsigned short*)alloc(4 * 128 * 64 * 2);
    float* biasAll = (float*)alloc(6 * 128 * 4);
    (void)n_in;

    // fp32 inter-layer state: prefer workspace; fall back to d_out placement.
    float* Sm;
    float* Sv;
    size_t used = (size_t)(w - (char*)d_ws);
    if (used + 2 * ((size_t)N * NH * 4 + 256) <= ws_size) {
        Sm = (float*)alloc((size_t)N * NH * 4);
        Sv = (float*)alloc((size_t)N * NH * 4);
    } else {
        Sm = out_mean;
        Sv = out_lv;
    }

    const int nbScan = (N + 1023) / 1024;
    const int nbR = (N + 63) / 64;
    const int nbAgg = (N + 15) / 16;
    const int nRange = (N + HWC - 1) / HWC;

    // weight prep
    prep_all<<<128, 256, 0, stream>>>(m0Wl, m0Wr, m0bl, v0Wl, v0Wr, v0bl,
                                      mRWl, mRWr, mRbl, vRWl, vRWr, vRbl,
                                      w0h, w0l, wlh, wll, biasAll);

    // CSR build: histogram -> rowptr -> cumulative offsets -> atomic-free fill
    int* partial = (int*)TLRu;  // scratch; fully consumed before gemm0 overwrites
    count_hist<<<nRange * HCHC, 256, 0, stream>>>(dstI, partial, E, N);
    scan1p<<<nbScan, 256, 0, stream>>>(partial, rowptr, bsum, N);
    scan2<<<1, 256, 0, stream>>>(bsum, boff, nbScan);
    scan3<<<(N + 256) / 256 + 1, 256, 0, stream>>>(rowptr, boff, N, E);
    cumpart<<<(N + 255) / 256, 256, 0, stream>>>(partial, rowptr, N);
    fill_hist<<<nRange * HCHC, 256, 0, stream>>>(srcI, dstI, partial, col, E, N);

    // layer-0 GEMM (overwrites TLRu after fill consumed the partials)
    gemm_dual<<<nbR, 256, 0, stream>>>(x, x, w0h, w0l, biasAll, TLRu, 128, N);
    agg_fused<<<nbAgg, 256, 0, stream>>>(TLRu, rowptr, col, Sm, Sv, N);

    // layers 1..2 (K=64, fp32 state)
    for (int i = 0; i < 2; ++i) {
        const bool fin = (i == 1);
        gemm_dual<<<nbR, 256, 0, stream>>>(Sm, Sv,
                                           wlh + (size_t)(2 * i) * 8192,
                                           wll + (size_t)(2 * i) * 8192,
                                           biasAll + (2 + 2 * i) * 128, TLRu, 64, N);
        if (fin)
            agg_fused<<<nbAgg, 256, 0, stream>>>(TLRu, rowptr, col, out_mean, out_lv, N);
        else
            agg_fused<<<nbAgg, 256, 0, stream>>>(TLRu, rowptr, col, Sm, Sv, N);
    }

    // reparam + pool + FC head, one block per graph
    pool_head<<<G, 256, 0, stream>>>(out_mean, out_lv, eps, batch, fc1W, fc1b, fc2W, fc2b,
                                     out_ls, N);
}

// Round 16
// 395.721 us; speedup vs baseline: 1.2695x; 1.1037x over previous
//
#include <hip/hip_runtime.h>

#define NH 64
#define NCLS 2
#define HWC 32768  // histogram window (nodes per range), 128KB LDS
#define HCHC 64    // edge chunks per range (256 blocks total at N=100K)

typedef short short8 __attribute__((ext_vector_type(8)));
typedef float f32x4 __attribute__((ext_vector_type(4)));

__device__ inline unsigned short f2bf(float x) {
    unsigned u = __float_as_uint(x);
    unsigned r = (u + 0x7FFFu + ((u >> 16) & 1u)) >> 16;
    return (unsigned short)r;
}
__device__ inline float bf2f(unsigned short h) { return __uint_as_float(((unsigned)h) << 16); }
__device__ inline float bf2f_u(unsigned h) { return __uint_as_float(h << 16); }

__device__ inline void acc_u4(uint4 u, float4& am, float4& av) {
    am.x += __uint_as_float(u.x << 16);
    av.x += __uint_as_float(u.x & 0xffff0000u);
    am.y += __uint_as_float(u.y << 16);
    av.y += __uint_as_float(u.y & 0xffff0000u);
    am.z += __uint_as_float(u.z << 16);
    av.z += __uint_as_float(u.z & 0xffff0000u);
    am.w += __uint_as_float(u.w << 16);
    av.w += __uint_as_float(u.w & 0xffff0000u);
}

// ---------------- degree count: atomic-free two-level histogram ----------------
// 1024-thread blocks: 16 waves/CU (LDS caps at 1 block/CU) for latency hiding.

__launch_bounds__(1024)
__global__ void count_hist(const int* __restrict__ dst, int* __restrict__ partial,
                           int E, int n) {
    __shared__ int hist[HWC];
    const int tid = threadIdx.x;
    const int range = blockIdx.x / HCHC, chunk = blockIdx.x - range * HCHC;
    const int lo = range * HWC;
    const int hi = min(lo + HWC, n);
    for (int i = tid * 4; i < HWC; i += 4096) *(int4*)&hist[i] = make_int4(0, 0, 0, 0);
    __syncthreads();
    int cbeg = ((int)((long long)chunk * E / HCHC)) & ~3;
    int cend = (chunk == HCHC - 1) ? E : (((int)((long long)(chunk + 1) * E / HCHC)) & ~3);
    int aend = cbeg + ((cend - cbeg) & ~3);
    for (int i = cbeg + tid * 4; i + 3 < cend; i += 4096) {
        int4 d = *(const int4*)(dst + i);
        if (d.x >= lo && d.x < hi) atomicAdd(&hist[d.x - lo], 1);
        if (d.y >= lo && d.y < hi) atomicAdd(&hist[d.y - lo], 1);
        if (d.z >= lo && d.z < hi) atomicAdd(&hist[d.z - lo], 1);
        if (d.w >= lo && d.w < hi) atomicAdd(&hist[d.w - lo], 1);
    }
    if (tid < cend - aend) {
        int d = dst[aend + tid];
        if (d >= lo && d < hi) atomicAdd(&hist[d - lo], 1);
    }
    __syncthreads();
    int* pout = partial + ((size_t)range * HCHC + chunk) * HWC;
    for (int i = tid * 4; i < HWC; i += 4096) *(int4*)&pout[i] = *(const int4*)&hist[i];
}

// block exclusive scan over deg (deg computed on the fly from the partials)
__global__ void scan1p(const int* __restrict__ partial, int* __restrict__ out,
                       int* __restrict__ bsum, int n) {
    __shared__ int s[256];
    int tid = threadIdx.x;
    int base = blockIdx.x * 1024 + tid * 4;
    int4 acc = make_int4(0, 0, 0, 0);
    if (base < n) {
        int r = base / HWC;
        int ii = base - r * HWC;
        const int* pr = partial + (size_t)r * HCHC * HWC + ii;
#pragma unroll 8
        for (int k = 0; k < HCHC; ++k) {
            int4 v = *(const int4*)(pr + (size_t)k * HWC);
            acc.x += v.x;
            acc.y += v.y;
            acc.z += v.z;
            acc.w += v.w;
        }
    }
    int v0 = (base + 0 < n) ? acc.x : 0;
    int v1 = (base + 1 < n) ? acc.y : 0;
    int v2 = (base + 2 < n) ? acc.z : 0;
    int v3 = (base + 3 < n) ? acc.w : 0;
    int lsum = v0 + v1 + v2 + v3;
    s[tid] = lsum;
    __syncthreads();
    for (int off = 1; off < 256; off <<= 1) {
        int t = (tid >= off) ? s[tid - off] : 0;
        __syncthreads();
        s[tid] += t;
        __syncthreads();
    }
    int excl = s[tid] - lsum;
    if (base + 0 < n) out[base + 0] = excl;
    if (base + 1 < n) out[base + 1] = excl + v0;
    if (base + 2 < n) out[base + 2] = excl + v0 + v1;
    if (base + 3 < n) out[base + 3] = excl + v0 + v1 + v2;
    if (tid == 255) bsum[blockIdx.x] = s[255];
}

__global__ void scan2(const int* __restrict__ bsum, int* __restrict__ boff, int nb) {
    __shared__ int s[256];
    int tid = threadIdx.x;
    int v = (tid < nb) ? bsum[tid] : 0;
    s[tid] = v;
    __syncthreads();
    for (int off = 1; off < 256; off <<= 1) {
        int t = (tid >= off) ? s[tid - off] : 0;
        __syncthreads();
        s[tid] += t;
        __syncthreads();
    }
    if (tid < nb) boff[tid] = s[tid] - v;
}

__global__ void scan3(int* __restrict__ rowptr, const int* __restrict__ boff,
                      int n, int total) {
    int i = blockIdx.x * 256 + threadIdx.x;
    if (i < n) rowptr[i] += boff[i >> 10];
    else if (i == n) rowptr[n] = total;
}

// convert partial counts -> absolute col starting offsets (per node, per chunk)
__global__ void cumpart(int* __restrict__ partial, const int* __restrict__ rowptr, int n) {
    int i = blockIdx.x * 256 + threadIdx.x;
    if (i >= n) return;
    int r = i / HWC, ii = i - r * HWC;
    int* base = partial + (size_t)r * HCHC * HWC + ii;
    int run = rowptr[i];
#pragma unroll 8
    for (int k = 0; k < HCHC; ++k) {
        int v = base[(size_t)k * HWC];
        base[(size_t)k * HWC] = run;
        run += v;
    }
}

// atomic-free CSR fill: block (range,chunk), LDS cursors seeded from cumpart offsets.
// 1024 threads (16 waves/CU); XCD remap keeps each range's col window on 2 XCDs' L2.
__launch_bounds__(1024)
__global__ void fill_hist(const int* __restrict__ src, const int* __restrict__ dst,
                          const int* __restrict__ partial, int* __restrict__ col,
                          int E, int n) {
    __shared__ int cur[HWC];
    const int tid = threadIdx.x;
    int s0 = blockIdx.x;
    const int total = gridDim.x;
    if ((total & 7) == 0) {
        int per = total >> 3;
        s0 = (blockIdx.x & 7) * per + (blockIdx.x >> 3);
    }
    const int range = s0 / HCHC, chunk = s0 - range * HCHC;
    const int lo = range * HWC;
    const int hi = min(lo + HWC, n);
    const int* pin = partial + ((size_t)range * HCHC + chunk) * HWC;
    for (int i = tid * 4; i < HWC; i += 4096) *(int4*)&cur[i] = *(const int4*)&pin[i];
    __syncthreads();
    int cbeg = ((int)((long long)chunk * E / HCHC)) & ~3;
    int cend = (chunk == HCHC - 1) ? E : (((int)((long long)(chunk + 1) * E / HCHC)) & ~3);
    int aend = cbeg + ((cend - cbeg) & ~3);
    for (int i = cbeg + tid * 4; i + 3 < cend; i += 4096) {
        int4 d = *(const int4*)(dst + i);
        int4 sv = *(const int4*)(src + i);
        if (d.x >= lo && d.x < hi) col[atomicAdd(&cur[d.x - lo], 1)] = sv.x;
        if (d.y >= lo && d.y < hi) col[atomicAdd(&cur[d.y - lo], 1)] = sv.y;
        if (d.z >= lo && d.z < hi) col[atomicAdd(&cur[d.z - lo], 1)] = sv.z;
        if (d.w >= lo && d.w < hi) col[atomicAdd(&cur[d.w - lo], 1)] = sv.w;
    }
    if (tid < cend - aend) {
        int d = dst[aend + tid];
        if (d >= lo && d < hi) col[atomicAdd(&cur[d - lo], 1)] = src[aend + tid];
    }
}

// ---------------- weight prep (all 6 sets in one kernel) ----------------

__device__ void prep_one(const float* __restrict__ Wl, const float* __restrict__ Wr,
                         const float* __restrict__ bl, int K,
                         unsigned short* __restrict__ Wth, unsigned short* __restrict__ Wtl,
                         float* __restrict__ biasOut, int gid, int gsz) {
    int tot = 128 * K;
    for (int idx = gid; idx < tot; idx += gsz) {
        int c = idx / K, k = idx - c * K;
        float wv = (c < 64) ? Wl[(size_t)k * 64 + c] : Wr[(size_t)k * 64 + (c - 64)];
        unsigned short h = f2bf(wv);
        Wth[idx] = h;
        Wtl[idx] = f2bf(wv - bf2f(h));
    }
    for (int idx = gid; idx < 128; idx += gsz)
        biasOut[idx] = (idx < 64) ? 0.f : bl[idx - 64];
}

__global__ void prep_all(const float* __restrict__ m0Wl, const float* __restrict__ m0Wr,
                         const float* __restrict__ m0bl,
                         const float* __restrict__ v0Wl, const float* __restrict__ v0Wr,
                         const float* __restrict__ v0bl,
                         const float* __restrict__ mRWl, const float* __restrict__ mRWr,
                         const float* __restrict__ mRbl,
                         const float* __restrict__ vRWl, const float* __restrict__ vRWr,
                         const float* __restrict__ vRbl,
                         unsigned short* __restrict__ w0h, unsigned short* __restrict__ w0l,
                         unsigned short* __restrict__ wlh, unsigned short* __restrict__ wll,
                         float* __restrict__ biasAll) {
    int gid = blockIdx.x * 256 + threadIdx.x;
    int gsz = gridDim.x * 256;
    prep_one(m0Wl, m0Wr, m0bl, 128, w0h, w0l, biasAll, gid, gsz);
    prep_one(v0Wl, v0Wr, v0bl, 128, w0h + 128 * 128, w0l + 128 * 128, biasAll + 128, gid, gsz);
    for (int i = 0; i < 2; ++i) {
        prep_one(mRWl + (size_t)i * 4096, mRWr + (size_t)i * 4096, mRbl + (size_t)i * 64, 64,
                 wlh + (size_t)(2 * i) * 8192, wll + (size_t)(2 * i) * 8192,
                 biasAll + (2 + 2 * i) * 128, gid, gsz);
        prep_one(vRWl + (size_t)i * 4096, vRWr + (size_t)i * 4096, vRbl + (size_t)i * 64, 64,
                 wlh + (size_t)(2 * i + 1) * 8192, wll + (size_t)(2 * i + 1) * 8192,
                 biasAll + (2 + 2 * i + 1) * 128, gid, gsz);
    }
}

// ---------------- dual-path split-bf16 MFMA GEMM, fp32 A from global ----------------
// Pure GEMM, round-12-proven codegen (A loads inline, VGPR 84).
// Output TLRu[r*128+c] = bf16(mean) | bf16(var)<<16 ; c<64: TL, c>=64: TR(+bias).

__launch_bounds__(256)
__global__ void gemm_dual(const float* __restrict__ Am, const float* __restrict__ Av,
                          const unsigned short* __restrict__ Wh,  // [2][128*Kg]
                          const unsigned short* __restrict__ Wl,  // [2][128*Kg]
                          const float* __restrict__ bias,         // [2][128]
                          unsigned* __restrict__ TLRu, int Kg, int Nn) {
    __shared__ unsigned short Bh[128 * 72], Bl[128 * 72];
    const int tid = threadIdx.x;
    const int l = tid & 63, w = tid >> 6;
    const int rowbase = blockIdx.x * 64;
    const int r = rowbase + w * 16 + (l & 15);
    const bool rok = r < Nn;
    const int kofs = (l >> 4) * 8;
    f32x4 acc[2][8] = {};

    bool first = true;
    for (int k0 = 0; k0 < Kg; k0 += 64) {
#pragma unroll
        for (int p = 0; p < 2; ++p) {
            if (!first) __syncthreads();
            first = false;
            // stage B (one path) into LDS
#pragma unroll
            for (int q = 0; q < 4; ++q) {
                int lin = q * 256 + tid;
                int c = lin >> 3;
                int k8 = (lin & 7) << 3;
                *(short8*)&Bh[c * 72 + k8] =
                    *(const short8*)(Wh + (size_t)p * 128 * Kg + (size_t)c * Kg + k0 + k8);
                *(short8*)&Bl[c * 72 + k8] =
                    *(const short8*)(Wl + (size_t)p * 128 * Kg + (size_t)c * Kg + k0 + k8);
            }
            __syncthreads();
            const float* As = p ? Av : Am;
#pragma unroll
            for (int kk = 0; kk < 64; kk += 32) {
                short8 a_h = {}, a_l = {};
                if (rok) {
                    const float* xr = As + (size_t)r * Kg + k0 + kofs + kk;
                    float4 v0 = *(const float4*)xr;
                    float4 v1 = *(const float4*)(xr + 4);
                    float f[8] = {v0.x, v0.y, v0.z, v0.w, v1.x, v1.y, v1.z, v1.w};
#pragma unroll
                    for (int i = 0; i < 8; ++i) {
                        unsigned short h = f2bf(f[i]);
                        a_h[i] = (short)h;
                        a_l[i] = (short)f2bf(f[i] - bf2f(h));
                    }
                }
#pragma unroll
                for (int ct = 0; ct < 8; ++ct) {
                    const int br = (ct * 16 + (l & 15)) * 72 + kk + kofs;
                    short8 b_h = *(const short8*)&Bh[br];
                    short8 b_l = *(const short8*)&Bl[br];
                    acc[p][ct] = __builtin_amdgcn_mfma_f32_16x16x32_bf16(a_h, b_h, acc[p][ct], 0, 0, 0);
                    acc[p][ct] = __builtin_amdgcn_mfma_f32_16x16x32_bf16(a_h, b_l, acc[p][ct], 0, 0, 0);
                    acc[p][ct] = __builtin_amdgcn_mfma_f32_16x16x32_bf16(a_l, b_h, acc[p][ct], 0, 0, 0);
                }
            }
        }
    }
    const int r0 = rowbase + w * 16 + ((l >> 4) << 2);
#pragma unroll
    for (int ct = 0; ct < 8; ++ct) {
        int c = ct * 16 + (l & 15);
        float b0 = bias[c];
        float b1 = bias[128 + c];
#pragma unroll
        for (int i = 0; i < 4; ++i) {
            int rr = r0 + i;
            if (rr < Nn) {
                unsigned hm = f2bf(acc[0][ct][i] + b0);
                unsigned hv = f2bf(acc[1][ct][i] + b1);
                TLRu[(size_t)rr * 128 + c] = hm | (hv << 16);
            }
        }
    }
}

// ---------------- fused CSR aggregate (mean+var): relu(agg(TL)/deg + TR) ----------------

__launch_bounds__(256)
__global__ void agg_fused(const unsigned* __restrict__ TLRu,
                          const int* __restrict__ rowptr, const int* __restrict__ col,
                          float* __restrict__ outm, float* __restrict__ outv, int n) {
    int node = blockIdx.x * 16 + (threadIdx.x >> 4);
    if (node >= n) return;
    const int sub = threadIdx.x & 15;
    const int s = rowptr[node], e = rowptr[node + 1];
    float4 am0 = {0, 0, 0, 0}, av0 = {0, 0, 0, 0};
    float4 am1 = {0, 0, 0, 0}, av1 = {0, 0, 0, 0};
    int j = s;
    for (; j + 8 <= e; j += 8) {
        int c0 = col[j], c1 = col[j + 1], c2 = col[j + 2], c3 = col[j + 3];
        int c4 = col[j + 4], c5 = col[j + 5], c6 = col[j + 6], c7 = col[j + 7];
        uint4 u0 = ((const uint4*)(TLRu + (size_t)c0 * 128))[sub];
        uint4 u1 = ((const uint4*)(TLRu + (size_t)c1 * 128))[sub];
        uint4 u2 = ((const uint4*)(TLRu + (size_t)c2 * 128))[sub];
        uint4 u3 = ((const uint4*)(TLRu + (size_t)c3 * 128))[sub];
        uint4 u4 = ((const uint4*)(TLRu + (size_t)c4 * 128))[sub];
        uint4 u5 = ((const uint4*)(TLRu + (size_t)c5 * 128))[sub];
        uint4 u6 = ((const uint4*)(TLRu + (size_t)c6 * 128))[sub];
        uint4 u7 = ((const uint4*)(TLRu + (size_t)c7 * 128))[sub];
        acc_u4(u0, am0, av0);
        acc_u4(u1, am1, av1);
        acc_u4(u2, am0, av0);
        acc_u4(u3, am1, av1);
        acc_u4(u4, am0, av0);
        acc_u4(u5, am1, av1);
        acc_u4(u6, am0, av0);
        acc_u4(u7, am1, av1);
    }
    if (j + 4 <= e) {
        int c0 = col[j], c1 = col[j + 1], c2 = col[j + 2], c3 = col[j + 3];
        uint4 u0 = ((const uint4*)(TLRu + (size_t)c0 * 128))[sub];
        uint4 u1 = ((const uint4*)(TLRu + (size_t)c1 * 128))[sub];
        uint4 u2 = ((const uint4*)(TLRu + (size_t)c2 * 128))[sub];
        uint4 u3 = ((const uint4*)(TLRu + (size_t)c3 * 128))[sub];
        acc_u4(u0, am0, av0);
        acc_u4(u1, am1, av1);
        acc_u4(u2, am0, av0);
        acc_u4(u3, am1, av1);
        j += 4;
    }
    for (; j < e; ++j) {
        int c0 = col[j];
        uint4 u0 = ((const uint4*)(TLRu + (size_t)c0 * 128))[sub];
        acc_u4(u0, am0, av0);
    }
    am0.x += am1.x; am0.y += am1.y; am0.z += am1.z; am0.w += am1.w;
    av0.x += av1.x; av0.y += av1.y; av0.z += av1.z; av0.w += av1.w;

    float inv = 1.0f / (float)max(e - s, 1);
    uint4 t = ((const uint4*)(TLRu + (size_t)node * 128 + 64))[sub];
    float vm0 = fmaxf(fmaf(am0.x, inv, bf2f_u(t.x & 0xffff)), 0.f);
    float vv0 = fmaxf(fmaf(av0.x, inv, __uint_as_float(t.x & 0xffff0000u)), 0.f);
    float vm1 = fmaxf(fmaf(am0.y, inv, bf2f_u(t.y & 0xffff)), 0.f);
    float vv1 = fmaxf(fmaf(av0.y, inv, __uint_as_float(t.y & 0xffff0000u)), 0.f);
    float vm2 = fmaxf(fmaf(am0.z, inv, bf2f_u(t.z & 0xffff)), 0.f);
    float vv2 = fmaxf(fmaf(av0.z, inv, __uint_as_float(t.z & 0xffff0000u)), 0.f);
    float vm3 = fmaxf(fmaf(am0.w, inv, bf2f_u(t.w & 0xffff)), 0.f);
    float vv3 = fmaxf(fmaf(av0.w, inv, __uint_as_float(t.w & 0xffff0000u)), 0.f);
    size_t o = (size_t)node * 64 + sub * 4;
    *(float4*)(outm + o) = make_float4(vm0, vm1, vm2, vm3);
    *(float4*)(outv + o) = make_float4(vv0, vv1, vv2, vv3);
}

// ---------------- per-group: reparam + mean-pool + fc1 + relu + fc2 + log_softmax ----------------

__launch_bounds__(256)
__global__ void pool_head(const float* __restrict__ mean, const float* __restrict__ logv,
                          const float* __restrict__ eps, const int* __restrict__ batch,
                          const float* __restrict__ fc1W, const float* __restrict__ fc1b,
                          const float* __restrict__ fc2W, const float* __restrict__ fc2b,
                          float* __restrict__ out, int n) {
    __shared__ int se[2];
    __shared__ float4 red[256];
    __shared__ float pooled[64];
    __shared__ float hbuf[128];
    __shared__ float lg[2];
    const int g = blockIdx.x, tid = threadIdx.x;
    if (tid == 0 || tid == 64) {
        int key = g + (tid >> 6);
        int a = 0, b = n;
        while (a < b) {
            int m = (a + b) >> 1;
            if (batch[m] < key) a = m + 1;
            else b = m;
        }
        se[tid >> 6] = a;
    }
    __syncthreads();
    const int s = se[0], e = se[1];
    const int nof = tid >> 4, fq = tid & 15;
    float4 acc = make_float4(0.f, 0.f, 0.f, 0.f);
    for (int i = s + nof; i < e; i += 16) {
        size_t o = (size_t)i * 64 + fq * 4;
        float4 m4 = *(const float4*)(mean + o);
        float4 l4 = *(const float4*)(logv + o);
        float4 e4 = *(const float4*)(eps + o);
        acc.x += m4.x + e4.x * expf(0.5f * l4.x);
        acc.y += m4.y + e4.y * expf(0.5f * l4.y);
        acc.z += m4.z + e4.z * expf(0.5f * l4.z);
        acc.w += m4.w + e4.w * expf(0.5f * l4.w);
    }
    red[tid] = acc;
    __syncthreads();
    if (tid < 16) {
        float4 sum = red[fq];
        for (int j = 1; j < 16; ++j) {
            float4 r = red[j * 16 + fq];
            sum.x += r.x;
            sum.y += r.y;
            sum.z += r.z;
            sum.w += r.w;
        }
        float inv = 1.0f / (float)max(e - s, 1);
        pooled[fq * 4 + 0] = sum.x * inv;
        pooled[fq * 4 + 1] = sum.y * inv;
        pooled[fq * 4 + 2] = sum.z * inv;
        pooled[fq * 4 + 3] = sum.w * inv;
    }
    __syncthreads();
    if (tid < 128) {
        float a = fc1b[tid];
        for (int k = 0; k < 64; ++k) a = fmaf(pooled[k], fc1W[k * 128 + tid], a);
        hbuf[tid] = fmaxf(a, 0.f);
    }
    __syncthreads();
    if (tid < 2) {
        float a = fc2b[tid];
        for (int k = 0; k < 128; ++k) a = fmaf(hbuf[k], fc2W[k * 2 + tid], a);
        lg[tid] = a;
    }
    __syncthreads();
    if (tid < 2) {
        float m = fmaxf(lg[0], lg[1]);
        float lse = m + logf(expf(lg[0] - m) + expf(lg[1] - m));
        out[(size_t)g * 2 + tid] = lg[tid] - lse;
    }
}

extern "C" void kernel_launch(void* const* d_in, const int* in_sizes, int n_in,
                              void* d_out, int out_size, void* d_ws, size_t ws_size,
                              hipStream_t stream) {
    const int N = in_sizes[19];
    const int E = in_sizes[18] / 2;
    const int G = (out_size - 2 * N * NH) / NCLS;

    const float* x    = (const float*)d_in[0];
    const float* eps  = (const float*)d_in[1];
    const float* m0Wl = (const float*)d_in[2];
    const float* m0bl = (const float*)d_in[3];
    const float* m0Wr = (const float*)d_in[4];
    const float* mRWl = (const float*)d_in[5];
    const float* mRbl = (const float*)d_in[6];
    const float* mRWr = (const float*)d_in[7];
    const float* v0Wl = (const float*)d_in[8];
    const float* v0bl = (const float*)d_in[9];
    const float* v0Wr = (const float*)d_in[10];
    const float* vRWl = (const float*)d_in[11];
    const float* vRbl = (const float*)d_in[12];
    const float* vRWr = (const float*)d_in[13];
    const float* fc1W = (const float*)d_in[14];
    const float* fc1b = (const float*)d_in[15];
    const float* fc2W = (const float*)d_in[16];
    const float* fc2b = (const float*)d_in[17];
    const int* eidx   = (const int*)d_in[18];
    const int* batch  = (const int*)d_in[19];
    const int* srcI = eidx;
    const int* dstI = eidx + E;

    float* out_ls = (float*)d_out;
    float* out_mean = out_ls + (size_t)G * NCLS;
    float* out_lv = out_mean + (size_t)N * NH;

    char* w = (char*)d_ws;
    auto alloc = [&](size_t bytes) {
        char* p = w;
        w += (bytes + 255) & ~(size_t)255;
        return p;
    };
    int* rowptr = (int*)alloc((size_t)(N + 1) * 4);
    int* bsum = (int*)alloc(256 * 4);
    int* boff = (int*)alloc(256 * 4);
    int* col = (int*)alloc((size_t)E * 4);
    unsigned* TLRu = (unsigned*)alloc((size_t)N * 128 * 4);  // packed mean|var
    unsigned short* w0h = (unsigned short*)alloc(2 * 128 * 128 * 2);
    unsigned short* w0l = (unsigned short*)alloc(2 * 128 * 128 * 2);
    unsigned short* wlh = (unsigned short*)alloc(4 * 128 * 64 * 2);
    unsigned short* wll = (unsigned short*)alloc(4 * 128 * 64 * 2);
    float* biasAll = (float*)alloc(6 * 128 * 4);
    (void)n_in;

    const int nRange = (N + HWC - 1) / HWC;
    // partial histograms: nRange*HCHC*HWC ints. At N=100K: 33.5MB > TLRu(51MB ok).
    size_t partBytes = (size_t)nRange * HCHC * HWC * 4;
    int* partial;
    {
        size_t tlruBytes = (size_t)N * 128 * 4;
        partial = (partBytes <= tlruBytes) ? (int*)TLRu : (int*)alloc(partBytes);
    }

    // fp32 inter-layer state: prefer workspace; fall back to d_out placement.
    float* Sm;
    float* Sv;
    size_t used = (size_t)(w - (char*)d_ws);
    if (used + 2 * ((size_t)N * NH * 4 + 256) <= ws_size) {
        Sm = (float*)alloc((size_t)N * NH * 4);
        Sv = (float*)alloc((size_t)N * NH * 4);
    } else {
        Sm = out_mean;
        Sv = out_lv;
    }

    const int nbScan = (N + 1023) / 1024;
    const int nbR = (N + 63) / 64;
    const int nbAgg = (N + 15) / 16;

    // weight prep
    prep_all<<<128, 256, 0, stream>>>(m0Wl, m0Wr, m0bl, v0Wl, v0Wr, v0bl,
                                      mRWl, mRWr, mRbl, vRWl, vRWr, vRbl,
                                      w0h, w0l, wlh, wll, biasAll);

    // CSR build: histogram -> rowptr -> cumulative offsets -> atomic-free fill
    count_hist<<<nRange * HCHC, 1024, 0, stream>>>(dstI, partial, E, N);
    scan1p<<<nbScan, 256, 0, stream>>>(partial, rowptr, bsum, N);
    scan2<<<1, 256, 0, stream>>>(bsum, boff, nbScan);
    scan3<<<(N + 256) / 256 + 1, 256, 0, stream>>>(rowptr, boff, N, E);
    cumpart<<<(N + 255) / 256, 256, 0, stream>>>(partial, rowptr, N);
    fill_hist<<<nRange * HCHC, 1024, 0, stream>>>(srcI, dstI, partial, col, E, N);

    // layer-0 GEMM (overwrites TLRu after fill consumed the partials)
    gemm_dual<<<nbR, 256, 0, stream>>>(x, x, w0h, w0l, biasAll, TLRu, 128, N);
    agg_fused<<<nbAgg, 256, 0, stream>>>(TLRu, rowptr, col, Sm, Sv, N);

    // layers 1..2 (K=64, fp32 state)
    for (int i = 0; i < 2; ++i) {
        const bool fin = (i == 1);
        gemm_dual<<<nbR, 256, 0, stream>>>(Sm, Sv,
                                           wlh + (size_t)(2 * i) * 8192,
                                           wll + (size_t)(2 * i) * 8192,
                                           biasAll + (2 + 2 * i) * 128, TLRu, 64, N);
        if (fin)
            agg_fused<<<nbAgg, 256, 0, stream>>>(TLRu, rowptr, col, out_mean, out_lv, N);
        else
            agg_fused<<<nbAgg, 256, 0, stream>>>(TLRu, rowptr, col, Sm, Sv, N);
    }

    // reparam + pool + FC head, one block per graph
    pool_head<<<G, 256, 0, stream>>>(out_mean, out_lv, eps, batch, fc1W, fc1b, fc2W, fc2b,
                                     out_ls, N);
}